// Round 1
// baseline (1079.143 us; speedup 1.0000x reference)
//
#include <hip/hip_runtime.h>

typedef __attribute__((ext_vector_type(8))) short short8;
typedef __attribute__((ext_vector_type(4))) float floatx4;

#define MFMA16(a,b,c) __builtin_amdgcn_mfma_f32_16x16x32_bf16(a,b,c,0,0,0)

// fp32 -> bf16 round-to-nearest-even (hand-rolled; inputs finite)
static __device__ __forceinline__ unsigned short f2b(float f){
  union { float f; unsigned int u; } c; c.f = f;
  unsigned int u = c.u;
  u += 0x7fffu + ((u >> 16) & 1u);
  return (unsigned short)(u >> 16);
}

// ---------------- weight transpose + fp32->bf16 convert ----------------
// W: K x N fp32 row-major  ->  Wt: N x K bf16 row-major
__global__ __launch_bounds__(256) void transpose_cvt(
    const float* __restrict__ W, unsigned short* __restrict__ Wt, int K, int N){
  __shared__ float tile[32][33];
  const int tx = threadIdx.x & 31;
  const int ty = threadIdx.x >> 5;   // 0..7
  const int nx = blockIdx.x * 32, kx = blockIdx.y * 32;
  #pragma unroll
  for (int i = ty; i < 32; i += 8)
    tile[i][tx] = W[(size_t)(kx + i) * N + nx + tx];
  __syncthreads();
  #pragma unroll
  for (int i = ty; i < 32; i += 8)
    Wt[(size_t)(nx + i) * K + kx + tx] = f2b(tile[tx][i]);
}

// ---------------- layernorm (fp32 in, bf16 out), C=1024, 1 block/row ----------------
__global__ __launch_bounds__(256) void ln_kernel(
    const float* __restrict__ x, const float* __restrict__ g,
    const float* __restrict__ b, unsigned short* __restrict__ out){
  const int row = blockIdx.x, tid = threadIdx.x;
  const float4 v = reinterpret_cast<const float4*>(x + (size_t)row * 1024)[tid];
  float s  = v.x + v.y + v.z + v.w;
  float s2 = v.x*v.x + v.y*v.y + v.z*v.z + v.w*v.w;
  #pragma unroll
  for (int off = 1; off < 64; off <<= 1){
    s  += __shfl_xor(s,  off);
    s2 += __shfl_xor(s2, off);
  }
  __shared__ float red[8];
  const int wave = tid >> 6, lane = tid & 63;
  if (lane == 0){ red[wave] = s; red[4 + wave] = s2; }
  __syncthreads();
  s  = red[0] + red[1] + red[2] + red[3];
  s2 = red[4] + red[5] + red[6] + red[7];
  const float mu  = s * (1.f/1024.f);
  const float var = s2 * (1.f/1024.f) - mu * mu;
  const float rs  = rsqrtf(var + 1e-5f);
  const float4 gg = reinterpret_cast<const float4*>(g)[tid];
  const float4 bb = reinterpret_cast<const float4*>(b)[tid];
  ushort4 o;
  o.x = f2b((v.x - mu) * rs * gg.x + bb.x);
  o.y = f2b((v.y - mu) * rs * gg.y + bb.y);
  o.z = f2b((v.z - mu) * rs * gg.z + bb.z);
  o.w = f2b((v.w - mu) * rs * gg.w + bb.w);
  reinterpret_cast<ushort4*>(out + (size_t)row * 1024)[tid] = o;
}

// ---------------- GEMM: out = epilogue(A @ Bt^T + bias [+res]) ----------------
// A: M x K bf16 row-major; Bt: N x K bf16 row-major (pre-transposed weight)
// tile 64x64x32, 4 waves, each wave: 16 rows x 64 cols (4 MFMAs/K-step)
template<bool GELU, bool RES, bool OUTBF>
__global__ __launch_bounds__(256) void gemm_kernel(
    const unsigned short* __restrict__ A,
    const unsigned short* __restrict__ Bt,
    const float* __restrict__ bias,
    const float* __restrict__ res,
    float* __restrict__ outF,
    unsigned short* __restrict__ outB,
    int M, int N, int K)
{
  constexpr int LDA = 40;  // 32 + 8 pad (16B-aligned rows, spread banks)
  __shared__ __attribute__((aligned(16))) unsigned short sA[64 * LDA];
  __shared__ __attribute__((aligned(16))) unsigned short sB[64 * LDA];
  const int tid  = threadIdx.x;
  const int wave = tid >> 6, lane = tid & 63, quad = lane >> 4, l16 = lane & 15;
  const int m0 = blockIdx.x * 64, n0 = blockIdx.y * 64;
  const int srow = tid >> 2, scol = (tid & 3) * 8;
  const size_t arow = (size_t)(m0 + srow) * K + scol;
  const size_t brow = (size_t)(n0 + srow) * K + scol;

  floatx4 acc[4];
  #pragma unroll
  for (int nt = 0; nt < 4; nt++) acc[nt] = floatx4{0.f,0.f,0.f,0.f};

  for (int k0 = 0; k0 < K; k0 += 32){
    *reinterpret_cast<short8*>(&sA[srow*LDA + scol]) =
        *reinterpret_cast<const short8*>(&A[arow + k0]);
    *reinterpret_cast<short8*>(&sB[srow*LDA + scol]) =
        *reinterpret_cast<const short8*>(&Bt[brow + k0]);
    __syncthreads();
    const short8 af = *reinterpret_cast<const short8*>(&sA[(wave*16 + l16)*LDA + quad*8]);
    #pragma unroll
    for (int nt = 0; nt < 4; nt++){
      const short8 bf = *reinterpret_cast<const short8*>(&sB[(nt*16 + l16)*LDA + quad*8]);
      acc[nt] = MFMA16(af, bf, acc[nt]);
    }
    __syncthreads();
  }

  #pragma unroll
  for (int nt = 0; nt < 4; nt++){
    const int col = n0 + nt*16 + l16;
    const float bi = bias[col];
    #pragma unroll
    for (int r = 0; r < 4; r++){
      const int row = m0 + wave*16 + quad*4 + r;
      float val = acc[nt][r] + bi;
      if (GELU){
        const float t = 0.7978845608028654f * (val + 0.044715f * val * val * val);
        val = 0.5f * val * (1.f + tanhf(t));
      }
      if (RES) val += res[(size_t)row * N + col];
      if (OUTBF) outB[(size_t)row * N + col] = f2b(val);
      else       outF[(size_t)row * N + col] = val;
    }
  }
}

// ---------------- flash attention, causal, D=64, H=16, T=2048 ----------------
// grid: (T/64, B*H); 1 wg = 64 Q rows of one (b,h); 4 waves x 16 rows
__global__ __launch_bounds__(256) void attn_kernel(
    const unsigned short* __restrict__ Q,
    const unsigned short* __restrict__ K,
    const unsigned short* __restrict__ V,
    unsigned short* __restrict__ O)
{
  constexpr int T = 2048, CDIM = 1024;
  constexpr int LDK = 72, LDV = 40, LDP = 40;
  __shared__ __attribute__((aligned(16))) unsigned short sK[32 * LDK];
  __shared__ __attribute__((aligned(16))) unsigned short sVt[64 * LDV];
  __shared__ __attribute__((aligned(16))) unsigned short sP[4][16 * LDP];

  const int tid = threadIdx.x, wave = tid >> 6, lane = tid & 63;
  const int quad = lane >> 4, l16 = lane & 15;
  const int q0 = blockIdx.x * 64;
  const int bh = blockIdx.y, b = bh >> 4, h = bh & 15;
  const size_t base = (size_t)b * T * CDIM + h * 64;

  const int qrow = q0 + wave*16 + l16;
  const short8 qf0 = *reinterpret_cast<const short8*>(&Q[base + (size_t)qrow*CDIM + quad*8]);
  const short8 qf1 = *reinterpret_cast<const short8*>(&Q[base + (size_t)qrow*CDIM + 32 + quad*8]);

  float m_i[4], l_i[4];
  floatx4 o_acc[4];
  #pragma unroll
  for (int r = 0; r < 4; r++){ m_i[r] = -INFINITY; l_i[r] = 0.f; }
  #pragma unroll
  for (int nt = 0; nt < 4; nt++) o_acc[nt] = floatx4{0.f,0.f,0.f,0.f};

  const int trow = tid >> 3, tcol = (tid & 7) * 8;
  const int kend = q0 + 64;

  for (int k0 = 0; k0 < kend; k0 += 32){
    __syncthreads();  // prev-iter LDS reads done before restage
    *reinterpret_cast<short8*>(&sK[trow*LDK + tcol]) =
        *reinterpret_cast<const short8*>(&K[base + (size_t)(k0 + trow)*CDIM + tcol]);
    const short8 vv = *reinterpret_cast<const short8*>(&V[base + (size_t)(k0 + trow)*CDIM + tcol]);
    #pragma unroll
    for (int j = 0; j < 8; j++)
      sVt[(tcol + j)*LDV + trow] = ((const unsigned short*)&vv)[j];
    __syncthreads();

    // S = Q K^T (two 16-key subtiles), scale, causal mask
    float s[2][4];
    #pragma unroll
    for (int sub = 0; sub < 2; sub++){
      floatx4 sacc = floatx4{0.f,0.f,0.f,0.f};
      const short8 kf0 = *reinterpret_cast<const short8*>(&sK[(sub*16 + l16)*LDK + quad*8]);
      const short8 kf1 = *reinterpret_cast<const short8*>(&sK[(sub*16 + l16)*LDK + 32 + quad*8]);
      sacc = MFMA16(qf0, kf0, sacc);
      sacc = MFMA16(qf1, kf1, sacc);
      const int kk = k0 + sub*16 + l16;
      #pragma unroll
      for (int r = 0; r < 4; r++){
        const int qq = q0 + wave*16 + quad*4 + r;
        s[sub][r] = (kk <= qq) ? sacc[r] * 0.125f : -1e30f;
      }
    }

    // online softmax per owned row (rows quad*4+r, reduce across 16 lanes)
    #pragma unroll
    for (int r = 0; r < 4; r++){
      float mx = fmaxf(s[0][r], s[1][r]);
      #pragma unroll
      for (int off = 1; off < 16; off <<= 1) mx = fmaxf(mx, __shfl_xor(mx, off));
      const float mnew  = fmaxf(m_i[r], mx);
      const float alpha = __expf(m_i[r] - mnew);
      const float p0 = __expf(s[0][r] - mnew);
      const float p1 = __expf(s[1][r] - mnew);
      float rowsum = p0 + p1;
      #pragma unroll
      for (int off = 1; off < 16; off <<= 1) rowsum += __shfl_xor(rowsum, off);
      l_i[r] = l_i[r] * alpha + rowsum;
      m_i[r] = mnew;
      #pragma unroll
      for (int nt = 0; nt < 4; nt++) o_acc[nt][r] *= alpha;
      sP[wave][(quad*4 + r)*LDP + l16]      = f2b(p0);
      sP[wave][(quad*4 + r)*LDP + 16 + l16] = f2b(p1);
    }
    __syncthreads();  // P C-layout -> A-layout round trip

    // O += P V
    const short8 pf = *reinterpret_cast<const short8*>(&sP[wave][l16*LDP + quad*8]);
    #pragma unroll
    for (int nt = 0; nt < 4; nt++){
      const short8 vf = *reinterpret_cast<const short8*>(&sVt[(nt*16 + l16)*LDV + quad*8]);
      o_acc[nt] = MFMA16(pf, vf, o_acc[nt]);
    }
  }

  #pragma unroll
  for (int nt = 0; nt < 4; nt++){
    #pragma unroll
    for (int r = 0; r < 4; r++){
      const int row = q0 + wave*16 + quad*4 + r;
      const float val = o_acc[nt][r] / l_i[r];
      O[base + (size_t)row*CDIM + nt*16 + l16] = f2b(val);
    }
  }
}

// ---------------- launch ----------------
extern "C" void kernel_launch(void* const* d_in, const int* in_sizes, int n_in,
                              void* d_out, int out_size, void* d_ws, size_t ws_size,
                              hipStream_t stream){
  const float* x      = (const float*)d_in[0];
  const float* Wq     = (const float*)d_in[1];
  const float* bq     = (const float*)d_in[2];
  const float* Wk     = (const float*)d_in[3];
  const float* bk     = (const float*)d_in[4];
  const float* Wv     = (const float*)d_in[5];
  const float* bv     = (const float*)d_in[6];
  const float* Wo     = (const float*)d_in[7];
  const float* bo     = (const float*)d_in[8];
  const float* ln1_g  = (const float*)d_in[9];
  const float* ln1_b  = (const float*)d_in[10];
  const float* ln2_g  = (const float*)d_in[11];
  const float* ln2_b  = (const float*)d_in[12];
  const float* W_fc   = (const float*)d_in[13];
  const float* b_fc   = (const float*)d_in[14];
  const float* W_proj = (const float*)d_in[15];
  const float* b_proj = (const float*)d_in[16];
  float* out = (float*)d_out;
  char* ws = (char*)d_ws;
  const size_t MB = 1024 * 1024;

  unsigned short* bufA = (unsigned short*)(ws);           // 16MB: xn -> attn_out -> h
  unsigned short* qb   = (unsigned short*)(ws + 16*MB);   // 16MB
  unsigned short* kb   = (unsigned short*)(ws + 32*MB);   // 16MB
  unsigned short* vb   = (unsigned short*)(ws + 48*MB);   // 16MB
  unsigned short* fcb  = (unsigned short*)(ws + 16*MB);   // 64MB, reuses q/k/v (dead after attn)
  float* x2 = out;                                        // d_out doubles as fp32 residual buf
  unsigned short* Wqt  = (unsigned short*)(ws + 80*MB);
  unsigned short* Wkt  = (unsigned short*)(ws + 82*MB);
  unsigned short* Wvt  = (unsigned short*)(ws + 84*MB);
  unsigned short* Wot  = (unsigned short*)(ws + 86*MB);
  unsigned short* Wfct = (unsigned short*)(ws + 88*MB);   // 8MB
  unsigned short* Wpjt = (unsigned short*)(ws + 96*MB);   // 8MB

  dim3 tb(256);
  transpose_cvt<<<dim3(32, 32),  tb, 0, stream>>>(Wq,     Wqt,  1024, 1024);
  transpose_cvt<<<dim3(32, 32),  tb, 0, stream>>>(Wk,     Wkt,  1024, 1024);
  transpose_cvt<<<dim3(32, 32),  tb, 0, stream>>>(Wv,     Wvt,  1024, 1024);
  transpose_cvt<<<dim3(32, 32),  tb, 0, stream>>>(Wo,     Wot,  1024, 1024);
  transpose_cvt<<<dim3(128, 32), tb, 0, stream>>>(W_fc,   Wfct, 1024, 4096);
  transpose_cvt<<<dim3(32, 128), tb, 0, stream>>>(W_proj, Wpjt, 4096, 1024);

  ln_kernel<<<8192, tb, 0, stream>>>(x, ln1_g, ln1_b, bufA);

  gemm_kernel<false,false,true><<<dim3(128,16), tb, 0, stream>>>(bufA, Wqt, bq, nullptr, nullptr, qb, 8192, 1024, 1024);
  gemm_kernel<false,false,true><<<dim3(128,16), tb, 0, stream>>>(bufA, Wkt, bk, nullptr, nullptr, kb, 8192, 1024, 1024);
  gemm_kernel<false,false,true><<<dim3(128,16), tb, 0, stream>>>(bufA, Wvt, bv, nullptr, nullptr, vb, 8192, 1024, 1024);

  attn_kernel<<<dim3(32, 64), tb, 0, stream>>>(qb, kb, vb, bufA);

  gemm_kernel<false,true,false><<<dim3(128,16), tb, 0, stream>>>(bufA, Wot, bo, x, x2, nullptr, 8192, 1024, 1024);

  ln_kernel<<<8192, tb, 0, stream>>>(x2, ln2_g, ln2_b, bufA);

  gemm_kernel<true,false,true><<<dim3(128,64), tb, 0, stream>>>(bufA, Wfct, b_fc, nullptr, nullptr, fcb, 8192, 4096, 1024);

  gemm_kernel<false,true,false><<<dim3(128,16), tb, 0, stream>>>(fcb, Wpjt, b_proj, x2, out, nullptr, 8192, 1024, 4096);
}

// Round 3
// 737.968 us; speedup vs baseline: 1.4623x; 1.4623x over previous
//
#include <hip/hip_runtime.h>

typedef __attribute__((ext_vector_type(8))) short short8;
typedef __attribute__((ext_vector_type(4))) float floatx4;
typedef unsigned short u16;

#define MFMA16(a,b,c) __builtin_amdgcn_mfma_f32_16x16x32_bf16(a,b,c,0,0,0)

typedef const __attribute__((address_space(1))) void* gas1;
typedef __attribute__((address_space(3))) void* las3;
static __device__ __forceinline__ void glds16(const void* g, void* l){
  __builtin_amdgcn_global_load_lds((gas1)g, (las3)l, 16, 0, 0);
}

// fp32 -> bf16 round-to-nearest-even
static __device__ __forceinline__ u16 f2b(float f){
  union { float f; unsigned int u; } c; c.f = f;
  unsigned int u = c.u;
  u += 0x7fffu + ((u >> 16) & 1u);
  return (u16)(u >> 16);
}

// ---------------- weight transpose + fp32->bf16: W[KxN] -> Wt[NxK] ----------------
__global__ __launch_bounds__(256) void transpose_cvt(
    const float* __restrict__ W, u16* __restrict__ Wt, int K, int N){
  __shared__ float tile[32][33];
  const int tx = threadIdx.x & 31;
  const int ty = threadIdx.x >> 5;
  const int nx = blockIdx.x * 32, kx = blockIdx.y * 32;
  #pragma unroll
  for (int i = ty; i < 32; i += 8)
    tile[i][tx] = W[(size_t)(kx + i) * N + nx + tx];
  __syncthreads();
  #pragma unroll
  for (int i = ty; i < 32; i += 8)
    Wt[(size_t)(nx + i) * K + kx + tx] = f2b(tile[tx][i]);
}

// ---------------- layernorm fp32 -> bf16, C=1024, 1 block/row ----------------
__global__ __launch_bounds__(256) void ln_kernel(
    const float* __restrict__ x, const float* __restrict__ g,
    const float* __restrict__ b, u16* __restrict__ out){
  const int row = blockIdx.x, tid = threadIdx.x;
  const float4 v = reinterpret_cast<const float4*>(x + (size_t)row * 1024)[tid];
  float s  = v.x + v.y + v.z + v.w;
  float s2 = v.x*v.x + v.y*v.y + v.z*v.z + v.w*v.w;
  #pragma unroll
  for (int off = 1; off < 64; off <<= 1){
    s  += __shfl_xor(s,  off);
    s2 += __shfl_xor(s2, off);
  }
  __shared__ float red[8];
  const int wave = tid >> 6, lane = tid & 63;
  if (lane == 0){ red[wave] = s; red[4 + wave] = s2; }
  __syncthreads();
  s  = red[0] + red[1] + red[2] + red[3];
  s2 = red[4] + red[5] + red[6] + red[7];
  const float mu  = s * (1.f/1024.f);
  const float var = s2 * (1.f/1024.f) - mu * mu;
  const float rs  = rsqrtf(var + 1e-5f);
  const float4 gg = reinterpret_cast<const float4*>(g)[tid];
  const float4 bb = reinterpret_cast<const float4*>(b)[tid];
  ushort4 o;
  o.x = f2b((v.x - mu) * rs * gg.x + bb.x);
  o.y = f2b((v.y - mu) * rs * gg.y + bb.y);
  o.z = f2b((v.z - mu) * rs * gg.z + bb.z);
  o.w = f2b((v.w - mu) * rs * gg.w + bb.w);
  reinterpret_cast<ushort4*>(out + (size_t)row * 1024)[tid] = o;
}

// ---------------- bias concat for fused QKV ----------------
__global__ __launch_bounds__(256) void bias_concat(
    const float* __restrict__ bq, const float* __restrict__ bk,
    const float* __restrict__ bv, float* __restrict__ o){
  const int i = blockIdx.x * 256 + threadIdx.x;
  if (i < 1024) o[i] = bq[i];
  else if (i < 2048) o[i] = bk[i - 1024];
  else if (i < 3072) o[i] = bv[i - 2048];
}

// ---------------- V transpose: qkv[(b,t)][2048+h*64+d] -> vtb[bh][d][t] ----------------
__global__ __launch_bounds__(256) void vtrans(
    const u16* __restrict__ qkv, u16* __restrict__ vtb){
  __shared__ __attribute__((aligned(16))) u16 ld[64][72];
  const int tid = threadIdx.x;
  const int bh = blockIdx.y, b = bh >> 4, h = bh & 15;
  const int t0 = blockIdx.x * 64;
  const int tr = tid >> 2, tc = (tid & 3) * 16;
  const u16* src = qkv + (size_t)(b*2048 + t0 + tr) * 3072 + 2048 + h*64 + tc;
  *reinterpret_cast<short8*>(&ld[tr][tc])     = *reinterpret_cast<const short8*>(src);
  *reinterpret_cast<short8*>(&ld[tr][tc + 8]) = *reinterpret_cast<const short8*>(src + 8);
  __syncthreads();
  const int d = tid >> 2;
  u16 tmp[16];
  #pragma unroll
  for (int j = 0; j < 16; j++) tmp[j] = ld[tc + j][d];
  u16* dst = vtb + (size_t)bh*64*2048 + (size_t)d*2048 + t0 + tc;
  *reinterpret_cast<short8*>(dst)     = *reinterpret_cast<short8*>(&tmp[0]);
  *reinterpret_cast<short8*>(dst + 8) = *reinterpret_cast<short8*>(&tmp[8]);
}

// ---------------- GEMM m97-style: 128x128 tile, BK=32, global_load_lds ----------------
// A: MxK bf16; Bt: NxK bf16; out = epilogue(A @ Bt^T + bias [+res])
// Staging: A-tile is 128x32x2B = 8KB; 256 thr x 16B = 4KB per glds16
// => TWO glds16 per operand per K-step (round-2 bug: had one -> half-filled LDS)
template<bool GELU, bool RES, bool OUTBF>
__global__ __launch_bounds__(256) void gemm128(
    const u16* __restrict__ A, const u16* __restrict__ Bt,
    const float* __restrict__ bias, const float* __restrict__ bias2,
    const float* __restrict__ bias3,
    const float* __restrict__ res,
    float* __restrict__ outF, u16* __restrict__ outB,
    int M, int N, int K)
{
  __shared__ __attribute__((aligned(16))) u16 sA[128 * 32];
  __shared__ __attribute__((aligned(16))) u16 sB[128 * 32];
  const int tid  = threadIdx.x;
  const int wave = tid >> 6, lane = tid & 63, quad = lane >> 4, l16 = lane & 15;
  const int m0 = blockIdx.x * 128, n0 = blockIdx.y * 128;
  const int wm = (wave >> 1) * 64, wn = (wave & 1) * 64;

  // staging: wave w covers 32 rows in two 16-row halves
  // lane -> row base + (lane>>2), col (lane&3)*8 ; LDS slot = base + lane*16B
  const u16* agp  = A  + (size_t)(m0 + wave*32 + (lane >> 2)) * K + (lane & 3) * 8;
  const u16* agp2 = agp + (size_t)16 * K;
  const u16* bgp  = Bt + (size_t)(n0 + wave*32 + (lane >> 2)) * K + (lane & 3) * 8;
  const u16* bgp2 = bgp + (size_t)16 * K;
  u16* alp  = sA + wave * 1024;        // rows wave*32 .. +16
  u16* alp2 = alp + 512;               // rows wave*32+16 .. +32
  u16* blp  = sB + wave * 1024;
  u16* blp2 = blp + 512;

  floatx4 acc[4][4];
  #pragma unroll
  for (int i = 0; i < 4; i++)
    #pragma unroll
    for (int nt = 0; nt < 4; nt++) acc[i][nt] = floatx4{0.f,0.f,0.f,0.f};

  for (int k0 = 0; k0 < K; k0 += 32){
    glds16(agp  + k0, alp);
    glds16(agp2 + k0, alp2);
    glds16(bgp  + k0, blp);
    glds16(bgp2 + k0, blp2);
    __syncthreads();
    short8 af[4], bf[4];
    #pragma unroll
    for (int i = 0; i < 4; i++)
      af[i] = *reinterpret_cast<const short8*>(&sA[(wm + i*16 + l16)*32 + quad*8]);
    #pragma unroll
    for (int nt = 0; nt < 4; nt++)
      bf[nt] = *reinterpret_cast<const short8*>(&sB[(wn + nt*16 + l16)*32 + quad*8]);
    #pragma unroll
    for (int i = 0; i < 4; i++)
      #pragma unroll
      for (int nt = 0; nt < 4; nt++)
        acc[i][nt] = MFMA16(af[i], bf[nt], acc[i][nt]);
    __syncthreads();
  }

  #pragma unroll
  for (int nt = 0; nt < 4; nt++){
    const int col = n0 + wn + nt*16 + l16;
    float bi;
    if (bias3) bi = (col < 1024) ? bias[col] : (col < 2048 ? bias2[col-1024] : bias3[col-2048]);
    else       bi = bias[col];
    #pragma unroll
    for (int i = 0; i < 4; i++){
      #pragma unroll
      for (int r = 0; r < 4; r++){
        const int row = m0 + wm + i*16 + quad*4 + r;
        float val = acc[i][nt][r] + bi;
        if (GELU){
          const float t = 0.7978845608028654f * (val + 0.044715f * val * val * val);
          val = val / (1.f + __expf(-2.f * t));   // 0.5v(1+tanh t) == v*sigmoid(2t)
        }
        if (RES) val += res[(size_t)row * N + col];
        if (OUTBF) outB[(size_t)row * N + col] = f2b(val);
        else       outF[(size_t)row * N + col] = val;
      }
    }
  }
}

// ---------------- flash attention, causal, D=64, H=16, T=2048, 64-key tiles ----------------
// grid (32, 64): x = q-tile (reversed for load balance), y = b*16+h
__global__ __launch_bounds__(256) void attn_kernel(
    const u16* __restrict__ qkv, const u16* __restrict__ vtb,
    u16* __restrict__ O)
{
  constexpr int T = 2048, LDQ = 3072;
  __shared__ __attribute__((aligned(16))) u16 sK0[64*32], sK1[64*32];
  __shared__ __attribute__((aligned(16))) u16 sV0[64*32], sV1[64*32];
  __shared__ __attribute__((aligned(16))) u16 sP[4][16*72];

  const int tid = threadIdx.x, wave = tid >> 6, lane = tid & 63;
  const int quad = lane >> 4, l16 = lane & 15;
  const int q0 = (gridDim.x - 1 - blockIdx.x) * 64;   // longest blocks dispatch first
  const int bh = blockIdx.y, b = bh >> 4, h = bh & 15;
  const u16* Qp = qkv + (size_t)b * T * LDQ + h * 64;
  const u16* Kp = Qp + 1024;
  const u16* Vt = vtb + (size_t)bh * 64 * T;

  const int qrow = q0 + wave*16 + l16;
  const short8 qf0 = *reinterpret_cast<const short8*>(&Qp[(size_t)qrow*LDQ + quad*8]);
  const short8 qf1 = *reinterpret_cast<const short8*>(&Qp[(size_t)qrow*LDQ + 32 + quad*8]);

  float m_i[4], l_i[4];
  floatx4 o_acc[4];
  #pragma unroll
  for (int r = 0; r < 4; r++){ m_i[r] = -INFINITY; l_i[r] = 0.f; }
  #pragma unroll
  for (int nt = 0; nt < 4; nt++) o_acc[nt] = floatx4{0.f,0.f,0.f,0.f};

  // staging lane mapping: row = wave*16 + (lane>>2), col = (lane&3)*8
  const int srow = wave*16 + (lane >> 2);
  const int scol = (lane & 3) * 8;

  for (int k0 = 0; k0 < q0 + 64; k0 += 64){
    glds16(Kp + (size_t)(k0 + srow)*LDQ + scol,      sK0 + wave*512);
    glds16(Kp + (size_t)(k0 + srow)*LDQ + 32 + scol, sK1 + wave*512);
    glds16(Vt + (size_t)srow*T + k0 + scol,          sV0 + wave*512);
    glds16(Vt + (size_t)srow*T + k0 + 32 + scol,     sV1 + wave*512);
    __syncthreads();

    // S = Q K^T over 4 16-key subtiles
    float s[4][4];
    #pragma unroll
    for (int sub = 0; sub < 4; sub++){
      floatx4 sa = floatx4{0.f,0.f,0.f,0.f};
      const short8 kf0 = *reinterpret_cast<const short8*>(&sK0[(sub*16 + l16)*32 + quad*8]);
      const short8 kf1 = *reinterpret_cast<const short8*>(&sK1[(sub*16 + l16)*32 + quad*8]);
      sa = MFMA16(qf0, kf0, sa);
      sa = MFMA16(qf1, kf1, sa);
      #pragma unroll
      for (int r = 0; r < 4; r++) s[sub][r] = sa[r] * 0.125f;
    }
    if (k0 == q0){  // diagonal tile: causal mask
      #pragma unroll
      for (int sub = 0; sub < 4; sub++){
        const int kk = k0 + sub*16 + l16;
        #pragma unroll
        for (int r = 0; r < 4; r++){
          const int qq = q0 + wave*16 + quad*4 + r;
          if (kk > qq) s[sub][r] = -1e30f;
        }
      }
    }

    // online softmax, rows owned per (quad, r); row spans the quad's 16 lanes
    #pragma unroll
    for (int r = 0; r < 4; r++){
      float mx = fmaxf(fmaxf(s[0][r], s[1][r]), fmaxf(s[2][r], s[3][r]));
      #pragma unroll
      for (int off = 1; off < 16; off <<= 1) mx = fmaxf(mx, __shfl_xor(mx, off));
      const float mnew  = fmaxf(m_i[r], mx);
      const float alpha = __expf(m_i[r] - mnew);
      float ps[4], rowsum = 0.f;
      #pragma unroll
      for (int sub = 0; sub < 4; sub++){ ps[sub] = __expf(s[sub][r] - mnew); rowsum += ps[sub]; }
      #pragma unroll
      for (int off = 1; off < 16; off <<= 1) rowsum += __shfl_xor(rowsum, off);
      l_i[r] = l_i[r] * alpha + rowsum;
      m_i[r] = mnew;
      #pragma unroll
      for (int nt = 0; nt < 4; nt++) o_acc[nt][r] *= alpha;
      #pragma unroll
      for (int sub = 0; sub < 4; sub++)
        sP[wave][(quad*4 + r)*72 + sub*16 + l16] = f2b(ps[sub]);
    }
    // no barrier: sP is per-wave; a wave's LDS ops execute in order

    const short8 pf0 = *reinterpret_cast<const short8*>(&sP[wave][l16*72 + quad*8]);
    const short8 pf1 = *reinterpret_cast<const short8*>(&sP[wave][l16*72 + 32 + quad*8]);
    #pragma unroll
    for (int nt = 0; nt < 4; nt++){
      const short8 vf0 = *reinterpret_cast<const short8*>(&sV0[(nt*16 + l16)*32 + quad*8]);
      const short8 vf1 = *reinterpret_cast<const short8*>(&sV1[(nt*16 + l16)*32 + quad*8]);
      o_acc[nt] = MFMA16(pf0, vf0, o_acc[nt]);
      o_acc[nt] = MFMA16(pf1, vf1, o_acc[nt]);
    }
    __syncthreads();  // all waves done reading sK/sV before restage
  }

  #pragma unroll
  for (int nt = 0; nt < 4; nt++){
    #pragma unroll
    for (int r = 0; r < 4; r++){
      const int q = q0 + wave*16 + quad*4 + r;
      O[(size_t)(b*T + q)*1024 + h*64 + nt*16 + l16] = f2b(o_acc[nt][r] / l_i[r]);
    }
  }
}

// ---------------- launch ----------------
extern "C" void kernel_launch(void* const* d_in, const int* in_sizes, int n_in,
                              void* d_out, int out_size, void* d_ws, size_t ws_size,
                              hipStream_t stream){
  const float* x      = (const float*)d_in[0];
  const float* Wq     = (const float*)d_in[1];
  const float* bq     = (const float*)d_in[2];
  const float* Wk     = (const float*)d_in[3];
  const float* bk     = (const float*)d_in[4];
  const float* Wv     = (const float*)d_in[5];
  const float* bv     = (const float*)d_in[6];
  const float* Wo     = (const float*)d_in[7];
  const float* bo     = (const float*)d_in[8];
  const float* ln1_g  = (const float*)d_in[9];
  const float* ln1_b  = (const float*)d_in[10];
  const float* ln2_g  = (const float*)d_in[11];
  const float* ln2_b  = (const float*)d_in[12];
  const float* W_fc   = (const float*)d_in[13];
  const float* b_fc   = (const float*)d_in[14];
  const float* W_proj = (const float*)d_in[15];
  const float* b_proj = (const float*)d_in[16];
  float* out = (float*)d_out;
  char* ws = (char*)d_ws;
  const size_t MB = 1024 * 1024;

  u16* bufA  = (u16*)(ws);            // 16MB: xn -> attn_out -> h  [8192][1024]
  u16* qkvb  = (u16*)(ws + 16*MB);    // 48MB: [8192][3072]
  u16* vtb   = (u16*)(ws + 64*MB);    // 16MB: [64][64][2048]
  u16* fcb   = (u16*)(ws + 16*MB);    // 64MB, reuses qkvb+vtb (dead after attn)
  float* x2  = out;                   // d_out doubles as fp32 residual buffer
  u16* Wqkvt = (u16*)(ws + 80*MB);    // 6MB: [3072][1024]
  u16* Wot   = (u16*)(ws + 86*MB);    // 2MB
  u16* Wfct  = (u16*)(ws + 88*MB);    // 8MB
  u16* Wpjt  = (u16*)(ws + 96*MB);    // 8MB
  float* bqkv= (float*)(ws + 104*MB); // 12KB

  dim3 tb(256);
  transpose_cvt<<<dim3(32, 32),  tb, 0, stream>>>(Wq,     Wqkvt,             1024, 1024);
  transpose_cvt<<<dim3(32, 32),  tb, 0, stream>>>(Wk,     Wqkvt + 1024*1024, 1024, 1024);
  transpose_cvt<<<dim3(32, 32),  tb, 0, stream>>>(Wv,     Wqkvt + 2048*1024, 1024, 1024);
  transpose_cvt<<<dim3(32, 32),  tb, 0, stream>>>(Wo,     Wot,               1024, 1024);
  transpose_cvt<<<dim3(128, 32), tb, 0, stream>>>(W_fc,   Wfct,              1024, 4096);
  transpose_cvt<<<dim3(32, 128), tb, 0, stream>>>(W_proj, Wpjt,              4096, 1024);
  bias_concat<<<dim3(12), tb, 0, stream>>>(bq, bk, bv, bqkv);

  ln_kernel<<<8192, tb, 0, stream>>>(x, ln1_g, ln1_b, bufA);

  // fused QKV: [8192,1024] @ [3072,1024]^T -> [8192,3072]
  gemm128<false,false,true><<<dim3(64,24), tb, 0, stream>>>(
      bufA, Wqkvt, bqkv, bqkv+1024, bqkv+2048, nullptr, nullptr, qkvb, 8192, 3072, 1024);

  vtrans<<<dim3(32, 64), tb, 0, stream>>>(qkvb, vtb);

  attn_kernel<<<dim3(32, 64), tb, 0, stream>>>(qkvb, vtb, bufA);

  gemm128<false,true,false><<<dim3(64,8), tb, 0, stream>>>(
      bufA, Wot, bo, nullptr, nullptr, x, x2, nullptr, 8192, 1024, 1024);

  ln_kernel<<<8192, tb, 0, stream>>>(x2, ln2_g, ln2_b, bufA);

  gemm128<true,false,true><<<dim3(64,32), tb, 0, stream>>>(
      bufA, Wfct, b_fc, nullptr, nullptr, nullptr, nullptr, fcb, 8192, 4096, 1024);

  gemm128<false,true,false><<<dim3(64,8), tb, 0, stream>>>(
      fcb, Wpjt, b_proj, nullptr, nullptr, x2, out, nullptr, 8192, 1024, 4096);
}

// Round 4
// 642.796 us; speedup vs baseline: 1.6788x; 1.1481x over previous
//
#include <hip/hip_runtime.h>

typedef __attribute__((ext_vector_type(8))) short short8;
typedef __attribute__((ext_vector_type(4))) short short4v;
typedef __attribute__((ext_vector_type(4))) float floatx4;
typedef unsigned short u16;

#define MFMA16(a,b,c) __builtin_amdgcn_mfma_f32_16x16x32_bf16(a,b,c,0,0,0)

typedef const __attribute__((address_space(1))) void* gas1;
typedef __attribute__((address_space(3))) void* las3;
static __device__ __forceinline__ void glds16(const void* g, void* l){
  __builtin_amdgcn_global_load_lds((gas1)g, (las3)l, 16, 0, 0);
}

// fp32 -> bf16 round-to-nearest-even
static __device__ __forceinline__ u16 f2b(float f){
  union { float f; unsigned int u; } c; c.f = f;
  unsigned int u = c.u;
  u += 0x7fffu + ((u >> 16) & 1u);
  return (u16)(u >> 16);
}

// ---------------- weight transpose + fp32->bf16: W[KxN] -> Wt[NxK] ----------------
__global__ __launch_bounds__(256) void transpose_cvt(
    const float* __restrict__ W, u16* __restrict__ Wt, int K, int N){
  __shared__ float tile[32][33];
  const int tx = threadIdx.x & 31;
  const int ty = threadIdx.x >> 5;
  const int nx = blockIdx.x * 32, kx = blockIdx.y * 32;
  #pragma unroll
  for (int i = ty; i < 32; i += 8)
    tile[i][tx] = W[(size_t)(kx + i) * N + nx + tx];
  __syncthreads();
  #pragma unroll
  for (int i = ty; i < 32; i += 8)
    Wt[(size_t)(nx + i) * K + kx + tx] = f2b(tile[tx][i]);
}

// ---------------- layernorm fp32 -> bf16, C=1024, 1 block/row ----------------
__global__ __launch_bounds__(256) void ln_kernel(
    const float* __restrict__ x, const float* __restrict__ g,
    const float* __restrict__ b, u16* __restrict__ out){
  const int row = blockIdx.x, tid = threadIdx.x;
  const float4 v = reinterpret_cast<const float4*>(x + (size_t)row * 1024)[tid];
  float s  = v.x + v.y + v.z + v.w;
  float s2 = v.x*v.x + v.y*v.y + v.z*v.z + v.w*v.w;
  #pragma unroll
  for (int off = 1; off < 64; off <<= 1){
    s  += __shfl_xor(s,  off);
    s2 += __shfl_xor(s2, off);
  }
  __shared__ float red[8];
  const int wave = tid >> 6, lane = tid & 63;
  if (lane == 0){ red[wave] = s; red[4 + wave] = s2; }
  __syncthreads();
  s  = red[0] + red[1] + red[2] + red[3];
  s2 = red[4] + red[5] + red[6] + red[7];
  const float mu  = s * (1.f/1024.f);
  const float var = s2 * (1.f/1024.f) - mu * mu;
  const float rs  = rsqrtf(var + 1e-5f);
  const float4 gg = reinterpret_cast<const float4*>(g)[tid];
  const float4 bb = reinterpret_cast<const float4*>(b)[tid];
  ushort4 o;
  o.x = f2b((v.x - mu) * rs * gg.x + bb.x);
  o.y = f2b((v.y - mu) * rs * gg.y + bb.y);
  o.z = f2b((v.z - mu) * rs * gg.z + bb.z);
  o.w = f2b((v.w - mu) * rs * gg.w + bb.w);
  reinterpret_cast<ushort4*>(out + (size_t)row * 1024)[tid] = o;
}

// ---------------- bias concat for fused QKV ----------------
__global__ __launch_bounds__(256) void bias_concat(
    const float* __restrict__ bq, const float* __restrict__ bk,
    const float* __restrict__ bv, float* __restrict__ o){
  const int i = blockIdx.x * 256 + threadIdx.x;
  if (i < 1024) o[i] = bq[i];
  else if (i < 2048) o[i] = bk[i - 1024];
  else if (i < 3072) o[i] = bv[i - 2048];
}

// ---------------- V transpose: qkv[(b,t)][2048+h*64+d] -> vtb[bh][d][t] ----------------
__global__ __launch_bounds__(256) void vtrans(
    const u16* __restrict__ qkv, u16* __restrict__ vtb){
  __shared__ __attribute__((aligned(16))) u16 ld[64][72];
  const int tid = threadIdx.x;
  const int bh = blockIdx.y, b = bh >> 4, h = bh & 15;
  const int t0 = blockIdx.x * 64;
  const int tr = tid >> 2, tc = (tid & 3) * 16;
  const u16* src = qkv + (size_t)(b*2048 + t0 + tr) * 3072 + 2048 + h*64 + tc;
  *reinterpret_cast<short8*>(&ld[tr][tc])     = *reinterpret_cast<const short8*>(src);
  *reinterpret_cast<short8*>(&ld[tr][tc + 8]) = *reinterpret_cast<const short8*>(src + 8);
  __syncthreads();
  const int d = tid >> 2;
  u16 tmp[16];
  #pragma unroll
  for (int j = 0; j < 16; j++) tmp[j] = ld[tc + j][d];
  u16* dst = vtb + (size_t)bh*64*2048 + (size_t)d*2048 + t0 + tc;
  *reinterpret_cast<short8*>(dst)     = *reinterpret_cast<short8*>(&tmp[0]);
  *reinterpret_cast<short8*>(dst + 8) = *reinterpret_cast<short8*>(&tmp[8]);
}

// ---------------- GEMM: 128x128 tile, BK=64 (two 32-col chunks), global_load_lds ----------------
// A: MxK bf16; Bt: NxK bf16; out = epilogue(A @ Bt^T + bias [+res]); K % 64 == 0
template<bool GELU, bool RES, bool OUTBF>
__global__ __launch_bounds__(256) void gemm128(
    const u16* __restrict__ A, const u16* __restrict__ Bt,
    const float* __restrict__ bias, const float* __restrict__ bias2,
    const float* __restrict__ bias3,
    const float* __restrict__ res,
    float* __restrict__ outF, u16* __restrict__ outB,
    int M, int N, int K)
{
  __shared__ __attribute__((aligned(16))) u16 sA[2][128 * 32];
  __shared__ __attribute__((aligned(16))) u16 sB[2][128 * 32];
  const int tid  = threadIdx.x;
  const int wave = tid >> 6, lane = tid & 63, quad = lane >> 4, l16 = lane & 15;
  const int m0 = blockIdx.x * 128, n0 = blockIdx.y * 128;
  const int wm = (wave >> 1) * 64, wn = (wave & 1) * 64;

  // staging: wave w covers rows [w*32, w*32+32) in two 16-row halves per chunk
  // lane -> row base + (lane>>2), col (lane&3)*8 ; LDS slot = base + lane*16B
  const size_t aoff = (size_t)(m0 + wave*32 + (lane >> 2)) * K + (lane & 3) * 8;
  const size_t boff = (size_t)(n0 + wave*32 + (lane >> 2)) * K + (lane & 3) * 8;
  const size_t half = (size_t)16 * K;
  u16* alp = sA[0] + wave * 1024;   // chunk stride = 128*32; half stride = 512
  u16* blp = sB[0] + wave * 1024;

  floatx4 acc[4][4];
  #pragma unroll
  for (int i = 0; i < 4; i++)
    #pragma unroll
    for (int nt = 0; nt < 4; nt++) acc[i][nt] = floatx4{0.f,0.f,0.f,0.f};

  for (int k0 = 0; k0 < K; k0 += 64){
    #pragma unroll
    for (int c = 0; c < 2; c++){
      glds16(A  + aoff + k0 + c*32,        alp + c*4096);
      glds16(A  + aoff + k0 + c*32 + half, alp + c*4096 + 512);
      glds16(Bt + boff + k0 + c*32,        blp + c*4096);
      glds16(Bt + boff + k0 + c*32 + half, blp + c*4096 + 512);
    }
    __syncthreads();
    #pragma unroll
    for (int c = 0; c < 2; c++){
      short8 af[4], bf[4];
      #pragma unroll
      for (int i = 0; i < 4; i++)
        af[i] = *reinterpret_cast<const short8*>(&sA[c][(wm + i*16 + l16)*32 + quad*8]);
      #pragma unroll
      for (int nt = 0; nt < 4; nt++)
        bf[nt] = *reinterpret_cast<const short8*>(&sB[c][(wn + nt*16 + l16)*32 + quad*8]);
      #pragma unroll
      for (int i = 0; i < 4; i++)
        #pragma unroll
        for (int nt = 0; nt < 4; nt++)
          acc[i][nt] = MFMA16(af[i], bf[nt], acc[i][nt]);
    }
    __syncthreads();
  }

  #pragma unroll
  for (int nt = 0; nt < 4; nt++){
    const int col = n0 + wn + nt*16 + l16;
    float bi;
    if (bias3) bi = (col < 1024) ? bias[col] : (col < 2048 ? bias2[col-1024] : bias3[col-2048]);
    else       bi = bias[col];
    #pragma unroll
    for (int i = 0; i < 4; i++){
      #pragma unroll
      for (int r = 0; r < 4; r++){
        const int row = m0 + wm + i*16 + quad*4 + r;
        float val = acc[i][nt][r] + bi;
        if (GELU){
          const float t = 0.7978845608028654f * (val + 0.044715f * val * val * val);
          val = val / (1.f + __expf(-2.f * t));   // 0.5v(1+tanh t) == v*sigmoid(2t)
        }
        if (RES) val += res[(size_t)row * N + col];
        if (OUTBF) outB[(size_t)row * N + col] = f2b(val);
        else       outF[(size_t)row * N + col] = val;
      }
    }
  }
}

// ---------------- flash attention (transposed-S), causal, D=64, H=16, T=2048 ----------------
// S^T = K·Q^T via operand swap: C col = lane&15 = q  ==> softmax is IN-LANE (16 scores/lane)
// grid (32, 64): x = q-tile (reversed for load balance), y = b*16+h
__global__ __launch_bounds__(256) void attn_kernel(
    const u16* __restrict__ qkv, const u16* __restrict__ vtb,
    u16* __restrict__ O)
{
  constexpr int T = 2048, LDQ = 3072, LDP = 72;
  __shared__ __attribute__((aligned(16))) u16 sK0[64*32], sK1[64*32];
  __shared__ __attribute__((aligned(16))) u16 sV0[64*32], sV1[64*32];
  __shared__ __attribute__((aligned(16))) u16 sP[4][16*LDP];

  const int tid = threadIdx.x, wave = tid >> 6, lane = tid & 63;
  const int quad = lane >> 4, l16 = lane & 15;
  const int q0 = (gridDim.x - 1 - blockIdx.x) * 64;   // longest blocks dispatch first
  const int bh = blockIdx.y, b = bh >> 4, h = bh & 15;
  const u16* Qp = qkv + (size_t)b * T * LDQ + h * 64;
  const u16* Kp = Qp + 1024;
  const u16* Vt = vtb + (size_t)bh * 64 * T;

  // B-operand Q fragments: row l16 = this wave's q, k = quad*8..
  const int q = q0 + wave*16 + l16;   // the q-row THIS LANE owns for softmax
  const short8 qf0 = *reinterpret_cast<const short8*>(&Qp[(size_t)q*LDQ + quad*8]);
  const short8 qf1 = *reinterpret_cast<const short8*>(&Qp[(size_t)q*LDQ + 32 + quad*8]);

  float m_i = -INFINITY, l_i = 0.f;   // per-lane = per-q state (replicated across quads)
  floatx4 o_acc[4];
  #pragma unroll
  for (int nt = 0; nt < 4; nt++) o_acc[nt] = floatx4{0.f,0.f,0.f,0.f};

  // staging lane mapping: row = wave*16 + (lane>>2), col = (lane&3)*8
  const int srow = wave*16 + (lane >> 2);
  const int scol = (lane & 3) * 8;
  const int asrc = (lane & 48) | (quad * 4);   // shfl source base: lane owning q-row quad*4+r

  for (int k0 = 0; k0 < q0 + 64; k0 += 64){
    glds16(Kp + (size_t)(k0 + srow)*LDQ + scol,      sK0 + wave*512);
    glds16(Kp + (size_t)(k0 + srow)*LDQ + 32 + scol, sK1 + wave*512);
    glds16(Vt + (size_t)srow*T + k0 + scol,          sV0 + wave*512);
    glds16(Vt + (size_t)srow*T + k0 + 32 + scol,     sV1 + wave*512);
    __syncthreads();

    // S^T = K·Q^T : s[sub][r] = score(key = k0+sub*16+quad*4+r, q)
    float s[4][4];
    #pragma unroll
    for (int sub = 0; sub < 4; sub++){
      floatx4 sa = floatx4{0.f,0.f,0.f,0.f};
      const short8 kf0 = *reinterpret_cast<const short8*>(&sK0[(sub*16 + l16)*32 + quad*8]);
      const short8 kf1 = *reinterpret_cast<const short8*>(&sK1[(sub*16 + l16)*32 + quad*8]);
      sa = MFMA16(kf0, qf0, sa);   // A=K, B=Q^T  -> rows=key, cols=q
      sa = MFMA16(kf1, qf1, sa);
      #pragma unroll
      for (int r = 0; r < 4; r++) s[sub][r] = sa[r];
    }
    if (k0 == q0){  // diagonal tile: causal mask (raw scores; scale folded into exp)
      #pragma unroll
      for (int sub = 0; sub < 4; sub++){
        #pragma unroll
        for (int r = 0; r < 4; r++){
          const int kk = k0 + sub*16 + quad*4 + r;
          if (kk > q) s[sub][r] = -1e30f;
        }
      }
    }

    // in-lane softmax over the 16 scores; reduce across quads with 2 shuffles
    float mx = s[0][0];
    #pragma unroll
    for (int sub = 0; sub < 4; sub++)
      #pragma unroll
      for (int r = 0; r < 4; r++) mx = fmaxf(mx, s[sub][r]);
    mx = fmaxf(mx, __shfl_xor(mx, 16));
    mx = fmaxf(mx, __shfl_xor(mx, 32));
    const float mnew  = fmaxf(m_i, mx);
    const float alpha = __expf(0.125f * (m_i - mnew));
    float p[4][4], rowsum = 0.f;
    #pragma unroll
    for (int sub = 0; sub < 4; sub++)
      #pragma unroll
      for (int r = 0; r < 4; r++){
        p[sub][r] = __expf(0.125f * (s[sub][r] - mnew));
        rowsum += p[sub][r];
      }
    rowsum += __shfl_xor(rowsum, 16);
    rowsum += __shfl_xor(rowsum, 32);
    l_i = l_i * alpha + rowsum;
    m_i = mnew;

    // rescale o_acc: row of o_acc = q0+wave*16+quad*4+r -> fetch that q's alpha
    float arow[4];
    #pragma unroll
    for (int r = 0; r < 4; r++) arow[r] = __shfl(alpha, asrc + r);
    #pragma unroll
    for (int nt = 0; nt < 4; nt++)
      #pragma unroll
      for (int r = 0; r < 4; r++) o_acc[nt][r] *= arow[r];

    // write P in A-layout: row = q (l16), cols = key; 4 contiguous keys per b64 write
    #pragma unroll
    for (int sub = 0; sub < 4; sub++){
      short4v pk;
      pk[0] = (short)f2b(p[sub][0]); pk[1] = (short)f2b(p[sub][1]);
      pk[2] = (short)f2b(p[sub][2]); pk[3] = (short)f2b(p[sub][3]);
      *reinterpret_cast<short4v*>(&sP[wave][l16*LDP + sub*16 + quad*4]) = pk;
    }
    // no barrier: sP is per-wave; a wave's LDS ops execute in order

    const short8 pf0 = *reinterpret_cast<const short8*>(&sP[wave][l16*LDP + quad*8]);
    const short8 pf1 = *reinterpret_cast<const short8*>(&sP[wave][l16*LDP + 32 + quad*8]);
    #pragma unroll
    for (int nt = 0; nt < 4; nt++){
      const short8 vf0 = *reinterpret_cast<const short8*>(&sV0[(nt*16 + l16)*32 + quad*8]);
      const short8 vf1 = *reinterpret_cast<const short8*>(&sV1[(nt*16 + l16)*32 + quad*8]);
      o_acc[nt] = MFMA16(pf0, vf0, o_acc[nt]);
      o_acc[nt] = MFMA16(pf1, vf1, o_acc[nt]);
    }
    __syncthreads();  // all waves done reading sK/sV before restage
  }

  float lrow[4];
  #pragma unroll
  for (int r = 0; r < 4; r++) lrow[r] = __shfl(l_i, asrc + r);
  #pragma unroll
  for (int nt = 0; nt < 4; nt++){
    #pragma unroll
    for (int r = 0; r < 4; r++){
      const int qq = q0 + wave*16 + quad*4 + r;
      O[(size_t)(b*T + qq)*1024 + h*64 + nt*16 + l16] = f2b(o_acc[nt][r] / lrow[r]);
    }
  }
}

// ---------------- launch ----------------
extern "C" void kernel_launch(void* const* d_in, const int* in_sizes, int n_in,
                              void* d_out, int out_size, void* d_ws, size_t ws_size,
                              hipStream_t stream){
  const float* x      = (const float*)d_in[0];
  const float* Wq     = (const float*)d_in[1];
  const float* bq     = (const float*)d_in[2];
  const float* Wk     = (const float*)d_in[3];
  const float* bk     = (const float*)d_in[4];
  const float* Wv     = (const float*)d_in[5];
  const float* bv     = (const float*)d_in[6];
  const float* Wo     = (const float*)d_in[7];
  const float* bo     = (const float*)d_in[8];
  const float* ln1_g  = (const float*)d_in[9];
  const float* ln1_b  = (const float*)d_in[10];
  const float* ln2_g  = (const float*)d_in[11];
  const float* ln2_b  = (const float*)d_in[12];
  const float* W_fc   = (const float*)d_in[13];
  const float* b_fc   = (const float*)d_in[14];
  const float* W_proj = (const float*)d_in[15];
  const float* b_proj = (const float*)d_in[16];
  float* out = (float*)d_out;
  char* ws = (char*)d_ws;
  const size_t MB = 1024 * 1024;

  u16* bufA  = (u16*)(ws);            // 16MB: xn -> attn_out -> h  [8192][1024]
  u16* qkvb  = (u16*)(ws + 16*MB);    // 48MB: [8192][3072]
  u16* vtb   = (u16*)(ws + 64*MB);    // 16MB: [64][64][2048]
  u16* fcb   = (u16*)(ws + 16*MB);    // 64MB, reuses qkvb+vtb (dead after attn)
  float* x2  = out;                   // d_out doubles as fp32 residual buffer
  u16* Wqkvt = (u16*)(ws + 80*MB);    // 6MB: [3072][1024]
  u16* Wot   = (u16*)(ws + 86*MB);    // 2MB
  u16* Wfct  = (u16*)(ws + 88*MB);    // 8MB
  u16* Wpjt  = (u16*)(ws + 96*MB);    // 8MB
  float* bqkv= (float*)(ws + 104*MB); // 12KB

  dim3 tb(256);
  transpose_cvt<<<dim3(32, 32),  tb, 0, stream>>>(Wq,     Wqkvt,             1024, 1024);
  transpose_cvt<<<dim3(32, 32),  tb, 0, stream>>>(Wk,     Wqkvt + 1024*1024, 1024, 1024);
  transpose_cvt<<<dim3(32, 32),  tb, 0, stream>>>(Wv,     Wqkvt + 2048*1024, 1024, 1024);
  transpose_cvt<<<dim3(32, 32),  tb, 0, stream>>>(Wo,     Wot,               1024, 1024);
  transpose_cvt<<<dim3(128, 32), tb, 0, stream>>>(W_fc,   Wfct,              1024, 4096);
  transpose_cvt<<<dim3(32, 128), tb, 0, stream>>>(W_proj, Wpjt,              4096, 1024);
  bias_concat<<<dim3(12), tb, 0, stream>>>(bq, bk, bv, bqkv);

  ln_kernel<<<8192, tb, 0, stream>>>(x, ln1_g, ln1_b, bufA);

  // fused QKV: [8192,1024] @ [3072,1024]^T -> [8192,3072]
  gemm128<false,false,true><<<dim3(64,24), tb, 0, stream>>>(
      bufA, Wqkvt, bqkv, bqkv+1024, bqkv+2048, nullptr, nullptr, qkvb, 8192, 3072, 1024);

  vtrans<<<dim3(32, 64), tb, 0, stream>>>(qkvb, vtb);

  attn_kernel<<<dim3(32, 64), tb, 0, stream>>>(qkvb, vtb, bufA);

  gemm128<false,true,false><<<dim3(64,8), tb, 0, stream>>>(
      bufA, Wot, bo, nullptr, nullptr, x, x2, nullptr, 8192, 1024, 1024);

  ln_kernel<<<8192, tb, 0, stream>>>(x2, ln2_g, ln2_b, bufA);

  gemm128<true,false,true><<<dim3(64,32), tb, 0, stream>>>(
      bufA, Wfct, b_fc, nullptr, nullptr, nullptr, nullptr, fcb, 8192, 4096, 1024);

  gemm128<false,true,false><<<dim3(64,8), tb, 0, stream>>>(
      fcb, Wpjt, b_proj, nullptr, nullptr, x2, out, nullptr, 8192, 1024, 4096);
}

// Round 5
// 612.728 us; speedup vs baseline: 1.7612x; 1.0491x over previous
//
#include <hip/hip_runtime.h>

typedef __attribute__((ext_vector_type(8))) short short8;
typedef __attribute__((ext_vector_type(4))) short short4v;
typedef __attribute__((ext_vector_type(4))) float floatx4;
typedef unsigned short u16;

#define MFMA16(a,b,c) __builtin_amdgcn_mfma_f32_16x16x32_bf16(a,b,c,0,0,0)

typedef const __attribute__((address_space(1))) void* gas1;
typedef __attribute__((address_space(3))) void* las3;
static __device__ __forceinline__ void glds16(const void* g, void* l){
  __builtin_amdgcn_global_load_lds((gas1)g, (las3)l, 16, 0, 0);
}

// fp32 -> bf16 round-to-nearest-even
static __device__ __forceinline__ u16 f2b(float f){
  union { float f; unsigned int u; } c; c.f = f;
  unsigned int u = c.u;
  u += 0x7fffu + ((u >> 16) & 1u);
  return (u16)(u >> 16);
}

// ---------------- weight transpose + fp32->bf16: W[KxN] -> Wt[NxK] ----------------
__global__ __launch_bounds__(256) void transpose_cvt(
    const float* __restrict__ W, u16* __restrict__ Wt, int K, int N){
  __shared__ float tile[32][33];
  const int tx = threadIdx.x & 31;
  const int ty = threadIdx.x >> 5;
  const int nx = blockIdx.x * 32, kx = blockIdx.y * 32;
  #pragma unroll
  for (int i = ty; i < 32; i += 8)
    tile[i][tx] = W[(size_t)(kx + i) * N + nx + tx];
  __syncthreads();
  #pragma unroll
  for (int i = ty; i < 32; i += 8)
    Wt[(size_t)(nx + i) * K + kx + tx] = f2b(tile[tx][i]);
}

// ---------------- layernorm fp32 -> bf16, C=1024, 1 block/row ----------------
__global__ __launch_bounds__(256) void ln_kernel(
    const float* __restrict__ x, const float* __restrict__ g,
    const float* __restrict__ b, u16* __restrict__ out){
  const int row = blockIdx.x, tid = threadIdx.x;
  const float4 v = reinterpret_cast<const float4*>(x + (size_t)row * 1024)[tid];
  float s  = v.x + v.y + v.z + v.w;
  float s2 = v.x*v.x + v.y*v.y + v.z*v.z + v.w*v.w;
  #pragma unroll
  for (int off = 1; off < 64; off <<= 1){
    s  += __shfl_xor(s,  off);
    s2 += __shfl_xor(s2, off);
  }
  __shared__ float red[8];
  const int wave = tid >> 6, lane = tid & 63;
  if (lane == 0){ red[wave] = s; red[4 + wave] = s2; }
  __syncthreads();
  s  = red[0] + red[1] + red[2] + red[3];
  s2 = red[4] + red[5] + red[6] + red[7];
  const float mu  = s * (1.f/1024.f);
  const float var = s2 * (1.f/1024.f) - mu * mu;
  const float rs  = rsqrtf(var + 1e-5f);
  const float4 gg = reinterpret_cast<const float4*>(g)[tid];
  const float4 bb = reinterpret_cast<const float4*>(b)[tid];
  ushort4 o;
  o.x = f2b((v.x - mu) * rs * gg.x + bb.x);
  o.y = f2b((v.y - mu) * rs * gg.y + bb.y);
  o.z = f2b((v.z - mu) * rs * gg.z + bb.z);
  o.w = f2b((v.w - mu) * rs * gg.w + bb.w);
  reinterpret_cast<ushort4*>(out + (size_t)row * 1024)[tid] = o;
}

// ---------------- bias concat for fused QKV ----------------
__global__ __launch_bounds__(256) void bias_concat(
    const float* __restrict__ bq, const float* __restrict__ bk,
    const float* __restrict__ bv, float* __restrict__ o){
  const int i = blockIdx.x * 256 + threadIdx.x;
  if (i < 1024) o[i] = bq[i];
  else if (i < 2048) o[i] = bk[i - 1024];
  else if (i < 3072) o[i] = bv[i - 2048];
}

// ---------------- GEMM: 128x128 tile, BK=64, global_load_lds, XOR bank swizzle ----------
// A: MxK bf16; Bt: NxK bf16; out = epilogue(A @ Bt^T + bias [+res]); K % 64 == 0
// Swizzle: LDS slot (row, chunk c) holds global 8-elem chunk (c ^ ((row>>1)&3)).
// QKVMODE: blocks with n0>=2048 write V^T to vtb ([bh][d][t]) instead of outB.
template<bool GELU, bool RES, bool OUTBF, bool QKVMODE>
__global__ __launch_bounds__(256) void gemm128(
    const u16* __restrict__ A, const u16* __restrict__ Bt,
    const float* __restrict__ bias, const float* __restrict__ bias2,
    const float* __restrict__ bias3,
    const float* __restrict__ res,
    float* __restrict__ outF, u16* __restrict__ outB,
    u16* __restrict__ vtb,
    int M, int N, int K)
{
  __shared__ __attribute__((aligned(16))) u16 sA[2][128 * 32];
  __shared__ __attribute__((aligned(16))) u16 sB[2][128 * 32];
  const int tid  = threadIdx.x;
  const int wave = tid >> 6, lane = tid & 63, quad = lane >> 4, l16 = lane & 15;
  const int m0 = blockIdx.x * 128, n0 = blockIdx.y * 128;
  const int wm = (wave >> 1) * 64, wn = (wave & 1) * 64;

  // staging: wave w covers rows [w*32, w*32+32) in two 16-row halves per chunk
  // lane -> row base+(lane>>2); global col chunk XOR-swizzled by (row>>1)&3
  const int scol = ((lane & 3) ^ ((lane >> 3) & 3)) * 8;
  const size_t aoff = (size_t)(m0 + wave*32 + (lane >> 2)) * K + scol;
  const size_t boff = (size_t)(n0 + wave*32 + (lane >> 2)) * K + scol;
  const size_t half = (size_t)16 * K;
  u16* alp = sA[0] + wave * 1024;   // chunk stride = 128*32; half stride = 512
  u16* blp = sB[0] + wave * 1024;
  // reader chunk offset (global chunk quad of row R: slot quad ^ ((R>>1)&3))
  const int qx = (quad ^ ((l16 >> 1) & 3)) * 8;

  floatx4 acc[4][4];
  #pragma unroll
  for (int i = 0; i < 4; i++)
    #pragma unroll
    for (int nt = 0; nt < 4; nt++) acc[i][nt] = floatx4{0.f,0.f,0.f,0.f};

  for (int k0 = 0; k0 < K; k0 += 64){
    #pragma unroll
    for (int c = 0; c < 2; c++){
      glds16(A  + aoff + k0 + c*32,        alp + c*4096);
      glds16(A  + aoff + k0 + c*32 + half, alp + c*4096 + 512);
      glds16(Bt + boff + k0 + c*32,        blp + c*4096);
      glds16(Bt + boff + k0 + c*32 + half, blp + c*4096 + 512);
    }
    __syncthreads();
    #pragma unroll
    for (int c = 0; c < 2; c++){
      short8 af[4], bf[4];
      #pragma unroll
      for (int i = 0; i < 4; i++)
        af[i] = *reinterpret_cast<const short8*>(&sA[c][(wm + i*16 + l16)*32 + qx]);
      #pragma unroll
      for (int nt = 0; nt < 4; nt++)
        bf[nt] = *reinterpret_cast<const short8*>(&sB[c][(wn + nt*16 + l16)*32 + qx]);
      #pragma unroll
      for (int i = 0; i < 4; i++)
        #pragma unroll
        for (int nt = 0; nt < 4; nt++)
          acc[i][nt] = MFMA16(af[i], bf[nt], acc[i][nt]);
    }
    __syncthreads();
  }

  if (QKVMODE && n0 >= 2048){
    // V^T epilogue: out[bh][d][t], 4 consecutive t per lane -> packed 8B stores
    #pragma unroll
    for (int nt = 0; nt < 4; nt++){
      const int hd = n0 + wn + nt*16 + l16 - 2048;   // h*64 + d
      const float bi = bias3[hd];
      u16* vcol = vtb + (size_t)(hd >> 6) * 131072 + (size_t)(hd & 63) * 2048;
      #pragma unroll
      for (int i = 0; i < 4; i++){
        const int t0 = m0 + wm + i*16 + quad*4;      // global row (b,t)
        const int bb = t0 >> 11, tt = t0 & 2047;
        short4v pk;
        #pragma unroll
        for (int r = 0; r < 4; r++) pk[r] = (short)f2b(acc[i][nt][r] + bi);
        *reinterpret_cast<short4v*>(vcol + (size_t)bb * 2097152 + tt) = pk;
      }
    }
    return;
  }

  #pragma unroll
  for (int nt = 0; nt < 4; nt++){
    const int col = n0 + wn + nt*16 + l16;
    float bi;
    if (QKVMODE) bi = (col < 1024) ? bias[col] : bias2[col-1024];
    else         bi = bias[col];
    #pragma unroll
    for (int i = 0; i < 4; i++){
      #pragma unroll
      for (int r = 0; r < 4; r++){
        const int row = m0 + wm + i*16 + quad*4 + r;
        float val = acc[i][nt][r] + bi;
        if (GELU){
          const float t = 0.7978845608028654f * (val + 0.044715f * val * val * val);
          val = val / (1.f + __expf(-2.f * t));   // 0.5v(1+tanh t) == v*sigmoid(2t)
        }
        if (RES) val += res[(size_t)row * N + col];
        if (OUTBF) outB[(size_t)row * N + col] = f2b(val);
        else       outF[(size_t)row * N + col] = val;
      }
    }
  }
}

// ---------------- flash attention (transposed-S), causal, D=64, H=16, T=2048 ----------------
// 128 Q-rows per block (two q-groups per wave share each staged K/V tile).
// S^T = K·Q^T via operand swap: C col = lane&15 = q ==> softmax IN-LANE.
// grid (16, 64): x = q-tile (reversed for load balance), y = b*16+h
__global__ __launch_bounds__(256) void attn_kernel(
    const u16* __restrict__ qkv, const u16* __restrict__ vtb,
    u16* __restrict__ O)
{
  constexpr int T = 2048, LDQ = 3072, LDP = 72;
  __shared__ __attribute__((aligned(16))) u16 sK0[64*32], sK1[64*32];
  __shared__ __attribute__((aligned(16))) u16 sV0[64*32], sV1[64*32];
  __shared__ __attribute__((aligned(16))) u16 sP[4][16*LDP];

  const int tid = threadIdx.x, wave = tid >> 6, lane = tid & 63;
  const int quad = lane >> 4, l16 = lane & 15;
  const int q0 = (gridDim.x - 1 - blockIdx.x) * 128;  // longest blocks dispatch first
  const int bh = blockIdx.y, b = bh >> 4, h = bh & 15;
  const u16* Qp = qkv + (size_t)b * T * LDQ + h * 64;
  const u16* Kp = Qp + 1024;
  const u16* Vt = vtb + (size_t)bh * 64 * T;

  const int qx = (quad ^ ((l16 >> 1) & 3)) * 8;       // swizzled fragment chunk

  int qg[2]; qg[0] = q0 + wave*16 + l16; qg[1] = qg[0] + 64;
  short8 qf[2][2];
  #pragma unroll
  for (int g = 0; g < 2; g++){
    qf[g][0] = *reinterpret_cast<const short8*>(&Qp[(size_t)qg[g]*LDQ + quad*8]);
    qf[g][1] = *reinterpret_cast<const short8*>(&Qp[(size_t)qg[g]*LDQ + 32 + quad*8]);
  }

  float m_i[2] = {-INFINITY, -INFINITY}, l_i[2] = {0.f, 0.f};
  floatx4 o_acc[2][4];
  #pragma unroll
  for (int g = 0; g < 2; g++)
    #pragma unroll
    for (int nt = 0; nt < 4; nt++) o_acc[g][nt] = floatx4{0.f,0.f,0.f,0.f};

  // staging: row = wave*16 + (lane>>2); col chunk XOR-swizzled by (row>>1)&3
  const int srow = wave*16 + (lane >> 2);
  const int scol = ((lane & 3) ^ ((lane >> 3) & 3)) * 8;
  const int asrc = (lane & 48) | (quad * 4);   // shfl source: lane owning q-row quad*4+r

  for (int k0 = 0; k0 < q0 + 128; k0 += 64){
    glds16(Kp + (size_t)(k0 + srow)*LDQ + scol,      sK0 + wave*512);
    glds16(Kp + (size_t)(k0 + srow)*LDQ + 32 + scol, sK1 + wave*512);
    glds16(Vt + (size_t)srow*T + k0 + scol,          sV0 + wave*512);
    glds16(Vt + (size_t)srow*T + k0 + 32 + scol,     sV1 + wave*512);
    __syncthreads();

    #pragma unroll
    for (int g = 0; g < 2; g++){
      if (g == 0 && k0 > q0) continue;   // tile fully masked for group 0

      // S^T = K·Q^T : s[sub][r] = score(key = k0+sub*16+quad*4+r, q = qg[g])
      float s[4][4];
      #pragma unroll
      for (int sub = 0; sub < 4; sub++){
        floatx4 sa = floatx4{0.f,0.f,0.f,0.f};
        const short8 kf0 = *reinterpret_cast<const short8*>(&sK0[(sub*16 + l16)*32 + qx]);
        const short8 kf1 = *reinterpret_cast<const short8*>(&sK1[(sub*16 + l16)*32 + qx]);
        sa = MFMA16(kf0, qf[g][0], sa);
        sa = MFMA16(kf1, qf[g][1], sa);
        #pragma unroll
        for (int r = 0; r < 4; r++) s[sub][r] = sa[r];
      }
      if (k0 == q0 + g*64){   // diagonal tile for this group
        #pragma unroll
        for (int sub = 0; sub < 4; sub++)
          #pragma unroll
          for (int r = 0; r < 4; r++){
            const int kk = k0 + sub*16 + quad*4 + r;
            if (kk > qg[g]) s[sub][r] = -1e30f;
          }
      }

      // in-lane softmax over 16 scores; cross-quad reduce with 2 shuffles
      float mx = s[0][0];
      #pragma unroll
      for (int sub = 0; sub < 4; sub++)
        #pragma unroll
        for (int r = 0; r < 4; r++) mx = fmaxf(mx, s[sub][r]);
      mx = fmaxf(mx, __shfl_xor(mx, 16));
      mx = fmaxf(mx, __shfl_xor(mx, 32));
      const float mnew  = fmaxf(m_i[g], mx);
      const float alpha = __expf(0.125f * (m_i[g] - mnew));
      float p[4][4], rowsum = 0.f;
      #pragma unroll
      for (int sub = 0; sub < 4; sub++)
        #pragma unroll
        for (int r = 0; r < 4; r++){
          p[sub][r] = __expf(0.125f * (s[sub][r] - mnew));
          rowsum += p[sub][r];
        }
      rowsum += __shfl_xor(rowsum, 16);
      rowsum += __shfl_xor(rowsum, 32);
      l_i[g] = l_i[g] * alpha + rowsum;
      m_i[g] = mnew;

      float arow[4];
      #pragma unroll
      for (int r = 0; r < 4; r++) arow[r] = __shfl(alpha, asrc + r);
      #pragma unroll
      for (int nt = 0; nt < 4; nt++)
        #pragma unroll
        for (int r = 0; r < 4; r++) o_acc[g][nt][r] *= arow[r];

      // P -> sP in A-layout (row = q = l16, cols = key); per-wave buffer,
      // reused across g: safe, a wave's DS ops execute in order.
      #pragma unroll
      for (int sub = 0; sub < 4; sub++){
        short4v pk;
        pk[0] = (short)f2b(p[sub][0]); pk[1] = (short)f2b(p[sub][1]);
        pk[2] = (short)f2b(p[sub][2]); pk[3] = (short)f2b(p[sub][3]);
        *reinterpret_cast<short4v*>(&sP[wave][l16*LDP + sub*16 + quad*4]) = pk;
      }
      const short8 pf0 = *reinterpret_cast<const short8*>(&sP[wave][l16*LDP + quad*8]);
      const short8 pf1 = *reinterpret_cast<const short8*>(&sP[wave][l16*LDP + 32 + quad*8]);
      #pragma unroll
      for (int nt = 0; nt < 4; nt++){
        const short8 vf0 = *reinterpret_cast<const short8*>(&sV0[(nt*16 + l16)*32 + qx]);
        const short8 vf1 = *reinterpret_cast<const short8*>(&sV1[(nt*16 + l16)*32 + qx]);
        o_acc[g][nt] = MFMA16(pf0, vf0, o_acc[g][nt]);
        o_acc[g][nt] = MFMA16(pf1, vf1, o_acc[g][nt]);
      }
    }
    __syncthreads();  // all waves done reading sK/sV before restage
  }

  #pragma unroll
  for (int g = 0; g < 2; g++){
    float lrow[4];
    #pragma unroll
    for (int r = 0; r < 4; r++) lrow[r] = __shfl(l_i[g], asrc + r);
    #pragma unroll
    for (int nt = 0; nt < 4; nt++){
      #pragma unroll
      for (int r = 0; r < 4; r++){
        const int row = q0 + g*64 + wave*16 + quad*4 + r;
        O[(size_t)(b*T + row)*1024 + h*64 + nt*16 + l16] = f2b(o_acc[g][nt][r] / lrow[r]);
      }
    }
  }
}

// ---------------- launch ----------------
extern "C" void kernel_launch(void* const* d_in, const int* in_sizes, int n_in,
                              void* d_out, int out_size, void* d_ws, size_t ws_size,
                              hipStream_t stream){
  const float* x      = (const float*)d_in[0];
  const float* Wq     = (const float*)d_in[1];
  const float* bq     = (const float*)d_in[2];
  const float* Wk     = (const float*)d_in[3];
  const float* bk     = (const float*)d_in[4];
  const float* Wv     = (const float*)d_in[5];
  const float* bv     = (const float*)d_in[6];
  const float* Wo     = (const float*)d_in[7];
  const float* bo     = (const float*)d_in[8];
  const float* ln1_g  = (const float*)d_in[9];
  const float* ln1_b  = (const float*)d_in[10];
  const float* ln2_g  = (const float*)d_in[11];
  const float* ln2_b  = (const float*)d_in[12];
  const float* W_fc   = (const float*)d_in[13];
  const float* b_fc   = (const float*)d_in[14];
  const float* W_proj = (const float*)d_in[15];
  const float* b_proj = (const float*)d_in[16];
  float* out = (float*)d_out;
  char* ws = (char*)d_ws;
  const size_t MB = 1024 * 1024;

  u16* bufA  = (u16*)(ws);            // 16MB: xn -> attn_out -> h  [8192][1024]
  u16* qkvb  = (u16*)(ws + 16*MB);    // 48MB: [8192][3072] (V third unused)
  u16* vtb   = (u16*)(ws + 64*MB);    // 16MB: [64][64][2048] (written by QKV GEMM)
  u16* fcb   = (u16*)(ws + 16*MB);    // 64MB, reuses qkvb+vtb (dead after attn)
  float* x2  = out;                   // d_out doubles as fp32 residual buffer
  u16* Wqkvt = (u16*)(ws + 80*MB);    // 6MB: [3072][1024]
  u16* Wot   = (u16*)(ws + 86*MB);    // 2MB
  u16* Wfct  = (u16*)(ws + 88*MB);    // 8MB
  u16* Wpjt  = (u16*)(ws + 96*MB);    // 8MB
  float* bqkv= (float*)(ws + 104*MB); // 12KB

  dim3 tb(256);
  transpose_cvt<<<dim3(32, 32),  tb, 0, stream>>>(Wq,     Wqkvt,             1024, 1024);
  transpose_cvt<<<dim3(32, 32),  tb, 0, stream>>>(Wk,     Wqkvt + 1024*1024, 1024, 1024);
  transpose_cvt<<<dim3(32, 32),  tb, 0, stream>>>(Wv,     Wqkvt + 2048*1024, 1024, 1024);
  transpose_cvt<<<dim3(32, 32),  tb, 0, stream>>>(Wo,     Wot,               1024, 1024);
  transpose_cvt<<<dim3(128, 32), tb, 0, stream>>>(W_fc,   Wfct,              1024, 4096);
  transpose_cvt<<<dim3(32, 128), tb, 0, stream>>>(W_proj, Wpjt,              4096, 1024);
  bias_concat<<<dim3(12), tb, 0, stream>>>(bq, bk, bv, bqkv);

  ln_kernel<<<8192, tb, 0, stream>>>(x, ln1_g, ln1_b, bufA);

  // fused QKV: [8192,1024] @ [3072,1024]^T -> Q,K into qkvb; V^T into vtb
  gemm128<false,false,true,true><<<dim3(64,24), tb, 0, stream>>>(
      bufA, Wqkvt, bqkv, bqkv+1024, bqkv+2048, nullptr, nullptr, qkvb, vtb, 8192, 3072, 1024);

  attn_kernel<<<dim3(16, 64), tb, 0, stream>>>(qkvb, vtb, bufA);

  gemm128<false,true,false,false><<<dim3(64,8), tb, 0, stream>>>(
      bufA, Wot, bo, nullptr, nullptr, x, x2, nullptr, nullptr, 8192, 1024, 1024);

  ln_kernel<<<8192, tb, 0, stream>>>(x2, ln2_g, ln2_b, bufA);

  gemm128<true,false,true,false><<<dim3(64,32), tb, 0, stream>>>(
      bufA, Wfct, b_fc, nullptr, nullptr, nullptr, nullptr, fcb, nullptr, 8192, 4096, 1024);

  gemm128<false,true,false,false><<<dim3(64,8), tb, 0, stream>>>(
      fcb, Wpjt, b_proj, nullptr, nullptr, x2, out, nullptr, nullptr, 8192, 1024, 4096);
}

// Round 6
// 559.083 us; speedup vs baseline: 1.9302x; 1.0960x over previous
//
#include <hip/hip_runtime.h>

typedef __attribute__((ext_vector_type(8))) short short8;
typedef __attribute__((ext_vector_type(4))) short short4v;
typedef __attribute__((ext_vector_type(4))) float floatx4;
typedef unsigned short u16;

#define MFMA16(a,b,c) __builtin_amdgcn_mfma_f32_16x16x32_bf16(a,b,c,0,0,0)

typedef const __attribute__((address_space(1))) void* gas1;
typedef __attribute__((address_space(3))) void* las3;
static __device__ __forceinline__ void glds16(const void* g, void* l){
  __builtin_amdgcn_global_load_lds((gas1)g, (las3)l, 16, 0, 0);
}

// fp32 -> bf16 round-to-nearest-even
static __device__ __forceinline__ u16 f2b(float f){
  union { float f; unsigned int u; } c; c.f = f;
  unsigned int u = c.u;
  u += 0x7fffu + ((u >> 16) & 1u);
  return (u16)(u >> 16);
}

// ---------------- weight transpose + fp32->bf16: W[KxN] -> Wt[NxK] ----------------
__global__ __launch_bounds__(256) void transpose_cvt(
    const float* __restrict__ W, u16* __restrict__ Wt, int K, int N){
  __shared__ float tile[32][33];
  const int tx = threadIdx.x & 31;
  const int ty = threadIdx.x >> 5;
  const int nx = blockIdx.x * 32, kx = blockIdx.y * 32;
  #pragma unroll
  for (int i = ty; i < 32; i += 8)
    tile[i][tx] = W[(size_t)(kx + i) * N + nx + tx];
  __syncthreads();
  #pragma unroll
  for (int i = ty; i < 32; i += 8)
    Wt[(size_t)(nx + i) * K + kx + tx] = f2b(tile[tx][i]);
}

// ---------------- layernorm fp32 -> bf16, C=1024, 1 block/row ----------------
__global__ __launch_bounds__(256) void ln_kernel(
    const float* __restrict__ x, const float* __restrict__ g,
    const float* __restrict__ b, u16* __restrict__ out){
  const int row = blockIdx.x, tid = threadIdx.x;
  const float4 v = reinterpret_cast<const float4*>(x + (size_t)row * 1024)[tid];
  float s  = v.x + v.y + v.z + v.w;
  float s2 = v.x*v.x + v.y*v.y + v.z*v.z + v.w*v.w;
  #pragma unroll
  for (int off = 1; off < 64; off <<= 1){
    s  += __shfl_xor(s,  off);
    s2 += __shfl_xor(s2, off);
  }
  __shared__ float red[8];
  const int wave = tid >> 6, lane = tid & 63;
  if (lane == 0){ red[wave] = s; red[4 + wave] = s2; }
  __syncthreads();
  s  = red[0] + red[1] + red[2] + red[3];
  s2 = red[4] + red[5] + red[6] + red[7];
  const float mu  = s * (1.f/1024.f);
  const float var = s2 * (1.f/1024.f) - mu * mu;
  const float rs  = rsqrtf(var + 1e-5f);
  const float4 gg = reinterpret_cast<const float4*>(g)[tid];
  const float4 bb = reinterpret_cast<const float4*>(b)[tid];
  ushort4 o;
  o.x = f2b((v.x - mu) * rs * gg.x + bb.x);
  o.y = f2b((v.y - mu) * rs * gg.y + bb.y);
  o.z = f2b((v.z - mu) * rs * gg.z + bb.z);
  o.w = f2b((v.w - mu) * rs * gg.w + bb.w);
  reinterpret_cast<ushort4*>(out + (size_t)row * 1024)[tid] = o;
}

// ---------------- bias concat for fused QKV ----------------
__global__ __launch_bounds__(256) void bias_concat(
    const float* __restrict__ bq, const float* __restrict__ bk,
    const float* __restrict__ bv, float* __restrict__ o){
  const int i = blockIdx.x * 256 + threadIdx.x;
  if (i < 1024) o[i] = bq[i];
  else if (i < 2048) o[i] = bk[i - 1024];
  else if (i < 3072) o[i] = bv[i - 2048];
}

// ---------------- GEMM: 128x128 tile, BK=64, global_load_lds, XOR bank swizzle ----------
// A: MxK bf16; Bt: NxK bf16; out = epilogue(A @ Bt^T + bias [+res]); K % 64 == 0
// Swizzle: LDS slot (row, chunk c) holds global 8-elem chunk (c ^ ((row>>1)&3)).
// QKVMODE: blocks with n0>=2048 write V^T to vtb ([bh][d][t]) instead of outB.
template<bool GELU, bool RES, bool OUTBF, bool QKVMODE>
__global__ __launch_bounds__(256) void gemm128(
    const u16* __restrict__ A, const u16* __restrict__ Bt,
    const float* __restrict__ bias, const float* __restrict__ bias2,
    const float* __restrict__ bias3,
    const float* __restrict__ res,
    float* __restrict__ outF, u16* __restrict__ outB,
    u16* __restrict__ vtb,
    int M, int N, int K)
{
  __shared__ __attribute__((aligned(16))) u16 sA[2][128 * 32];
  __shared__ __attribute__((aligned(16))) u16 sB[2][128 * 32];
  const int tid  = threadIdx.x;
  const int wave = tid >> 6, lane = tid & 63, quad = lane >> 4, l16 = lane & 15;
  const int m0 = blockIdx.x * 128, n0 = blockIdx.y * 128;
  const int wm = (wave >> 1) * 64, wn = (wave & 1) * 64;

  const int scol = ((lane & 3) ^ ((lane >> 3) & 3)) * 8;
  const size_t aoff = (size_t)(m0 + wave*32 + (lane >> 2)) * K + scol;
  const size_t boff = (size_t)(n0 + wave*32 + (lane >> 2)) * K + scol;
  const size_t half = (size_t)16 * K;
  u16* alp = sA[0] + wave * 1024;
  u16* blp = sB[0] + wave * 1024;
  const int qx = (quad ^ ((l16 >> 1) & 3)) * 8;

  floatx4 acc[4][4];
  #pragma unroll
  for (int i = 0; i < 4; i++)
    #pragma unroll
    for (int nt = 0; nt < 4; nt++) acc[i][nt] = floatx4{0.f,0.f,0.f,0.f};

  for (int k0 = 0; k0 < K; k0 += 64){
    #pragma unroll
    for (int c = 0; c < 2; c++){
      glds16(A  + aoff + k0 + c*32,        alp + c*4096);
      glds16(A  + aoff + k0 + c*32 + half, alp + c*4096 + 512);
      glds16(Bt + boff + k0 + c*32,        blp + c*4096);
      glds16(Bt + boff + k0 + c*32 + half, blp + c*4096 + 512);
    }
    __syncthreads();
    #pragma unroll
    for (int c = 0; c < 2; c++){
      short8 af[4], bf[4];
      #pragma unroll
      for (int i = 0; i < 4; i++)
        af[i] = *reinterpret_cast<const short8*>(&sA[c][(wm + i*16 + l16)*32 + qx]);
      #pragma unroll
      for (int nt = 0; nt < 4; nt++)
        bf[nt] = *reinterpret_cast<const short8*>(&sB[c][(wn + nt*16 + l16)*32 + qx]);
      #pragma unroll
      for (int i = 0; i < 4; i++)
        #pragma unroll
        for (int nt = 0; nt < 4; nt++)
          acc[i][nt] = MFMA16(af[i], bf[nt], acc[i][nt]);
    }
    __syncthreads();
  }

  if (QKVMODE && n0 >= 2048){
    // V^T epilogue: out[bh][d][t], 4 consecutive t per lane -> packed 8B stores
    #pragma unroll
    for (int nt = 0; nt < 4; nt++){
      const int hd = n0 + wn + nt*16 + l16 - 2048;   // h*64 + d
      const float bi = bias3[hd];
      u16* vcol = vtb + (size_t)(hd >> 6) * 131072 + (size_t)(hd & 63) * 2048;
      #pragma unroll
      for (int i = 0; i < 4; i++){
        const int t0 = m0 + wm + i*16 + quad*4;      // global row (b,t)
        const int bb = t0 >> 11, tt = t0 & 2047;
        short4v pk;
        #pragma unroll
        for (int r = 0; r < 4; r++) pk[r] = (short)f2b(acc[i][nt][r] + bi);
        *reinterpret_cast<short4v*>(vcol + (size_t)bb * 2097152 + tt) = pk;
      }
    }
    return;
  }

  #pragma unroll
  for (int nt = 0; nt < 4; nt++){
    const int col = n0 + wn + nt*16 + l16;
    float bi;
    if (QKVMODE) bi = (col < 1024) ? bias[col] : bias2[col-1024];
    else         bi = bias[col];
    #pragma unroll
    for (int i = 0; i < 4; i++){
      #pragma unroll
      for (int r = 0; r < 4; r++){
        const int row = m0 + wm + i*16 + quad*4 + r;
        float val = acc[i][nt][r] + bi;
        if (GELU){
          const float t = 0.7978845608028654f * (val + 0.044715f * val * val * val);
          val = val / (1.f + __expf(-2.f * t));   // 0.5v(1+tanh t) == v*sigmoid(2t)
        }
        if (RES) val += res[(size_t)row * N + col];
        if (OUTBF) outB[(size_t)row * N + col] = f2b(val);
        else       outF[(size_t)row * N + col] = val;
      }
    }
  }
}

// ---------------- flash attention (transposed-S), causal, D=64, H=16, T=2048 ----------------
// 128 Q-rows per block; length-balanced q-tile permutation; double-buffered K/V
// prefetch with ONE barrier per tile-iteration.
// grid (16, 64)
__global__ __launch_bounds__(256) void attn_kernel(
    const u16* __restrict__ qkv, const u16* __restrict__ vtb,
    u16* __restrict__ O)
{
  constexpr int T = 2048, LDQ = 3072, LDP = 72;
  __shared__ __attribute__((aligned(16))) u16 sK[2][2][64*32];
  __shared__ __attribute__((aligned(16))) u16 sV[2][2][64*32];
  __shared__ __attribute__((aligned(16))) u16 sP[4][16*LDP];

  const int tid = threadIdx.x, wave = tid >> 6, lane = tid & 63;
  const int quad = lane >> 4, l16 = lane & 15;

  // Length-balanced tile assignment: for any CU receiving blocks strided by 256
  // in linear id, the four causal lengths sum to the same total (68 iters).
  const int lin = blockIdx.y * 16 + blockIdx.x;
  const int j = lin & 15;
  const int bh = lin >> 4;              // 0..63 (head slot)
  const int kk4 = bh >> 4;              // 0..3
  const int jj = (j + ((kk4 & 2) << 2)) & 15;
  const int qt = (kk4 & 1) ? (15 - jj) : jj;
  const int q0 = qt * 128;
  const int b = bh >> 4, h = bh & 15;

  const u16* Qp = qkv + (size_t)b * T * LDQ + h * 64;
  const u16* Kp = Qp + 1024;
  const u16* Vt = vtb + (size_t)bh * 64 * T;

  const int qx = (quad ^ ((l16 >> 1) & 3)) * 8;       // swizzled fragment chunk

  int qg[2]; qg[0] = q0 + wave*16 + l16; qg[1] = qg[0] + 64;
  short8 qf[2][2];
  #pragma unroll
  for (int g = 0; g < 2; g++){
    qf[g][0] = *reinterpret_cast<const short8*>(&Qp[(size_t)qg[g]*LDQ + quad*8]);
    qf[g][1] = *reinterpret_cast<const short8*>(&Qp[(size_t)qg[g]*LDQ + 32 + quad*8]);
  }

  float m_i[2] = {-INFINITY, -INFINITY}, l_i[2] = {0.f, 0.f};
  floatx4 o_acc[2][4];
  #pragma unroll
  for (int g = 0; g < 2; g++)
    #pragma unroll
    for (int nt = 0; nt < 4; nt++) o_acc[g][nt] = floatx4{0.f,0.f,0.f,0.f};

  // staging: row = wave*16 + (lane>>2); col chunk XOR-swizzled by (row>>1)&3
  const int srow = wave*16 + (lane >> 2);
  const int scol = ((lane & 3) ^ ((lane >> 3) & 3)) * 8;
  const int asrc = (lane & 48) | (quad * 4);   // shfl source: lane owning q-row quad*4+r

  const int kend = q0 + 128;

  // prefetch tile 0 into buf 0
  {
    glds16(Kp + (size_t)srow*LDQ + scol,      sK[0][0] + wave*512);
    glds16(Kp + (size_t)srow*LDQ + 32 + scol, sK[0][1] + wave*512);
    glds16(Vt + (size_t)srow*T + scol,        sV[0][0] + wave*512);
    glds16(Vt + (size_t)srow*T + 32 + scol,   sV[0][1] + wave*512);
  }

  int buf = 0;
  for (int k0 = 0; k0 < kend; k0 += 64, buf ^= 1){
    __syncthreads();   // staged tile `buf` ready; all waves past reads of buf^1
    if (k0 + 64 < kend){
      const int kn = k0 + 64;
      glds16(Kp + (size_t)(kn + srow)*LDQ + scol,      sK[buf^1][0] + wave*512);
      glds16(Kp + (size_t)(kn + srow)*LDQ + 32 + scol, sK[buf^1][1] + wave*512);
      glds16(Vt + (size_t)srow*T + kn + scol,          sV[buf^1][0] + wave*512);
      glds16(Vt + (size_t)srow*T + kn + 32 + scol,     sV[buf^1][1] + wave*512);
    }

    #pragma unroll
    for (int g = 0; g < 2; g++){
      if (g == 0 && k0 > q0) continue;   // tile fully masked for group 0

      // S^T = K·Q^T : s[sub][r] = score(key = k0+sub*16+quad*4+r, q = qg[g])
      float s[4][4];
      #pragma unroll
      for (int sub = 0; sub < 4; sub++){
        floatx4 sa = floatx4{0.f,0.f,0.f,0.f};
        const short8 kf0 = *reinterpret_cast<const short8*>(&sK[buf][0][(sub*16 + l16)*32 + qx]);
        const short8 kf1 = *reinterpret_cast<const short8*>(&sK[buf][1][(sub*16 + l16)*32 + qx]);
        sa = MFMA16(kf0, qf[g][0], sa);
        sa = MFMA16(kf1, qf[g][1], sa);
        #pragma unroll
        for (int r = 0; r < 4; r++) s[sub][r] = sa[r];
      }
      if (k0 == q0 + g*64){   // diagonal tile for this group
        #pragma unroll
        for (int sub = 0; sub < 4; sub++)
          #pragma unroll
          for (int r = 0; r < 4; r++){
            const int kidx = k0 + sub*16 + quad*4 + r;
            if (kidx > qg[g]) s[sub][r] = -1e30f;
          }
      }

      // in-lane softmax over 16 scores; cross-quad reduce with 2 shuffles
      float mx = s[0][0];
      #pragma unroll
      for (int sub = 0; sub < 4; sub++)
        #pragma unroll
        for (int r = 0; r < 4; r++) mx = fmaxf(mx, s[sub][r]);
      mx = fmaxf(mx, __shfl_xor(mx, 16));
      mx = fmaxf(mx, __shfl_xor(mx, 32));
      const float mnew  = fmaxf(m_i[g], mx);
      const float alpha = __expf(0.125f * (m_i[g] - mnew));
      float p[4][4], rowsum = 0.f;
      #pragma unroll
      for (int sub = 0; sub < 4; sub++)
        #pragma unroll
        for (int r = 0; r < 4; r++){
          p[sub][r] = __expf(0.125f * (s[sub][r] - mnew));
          rowsum += p[sub][r];
        }
      rowsum += __shfl_xor(rowsum, 16);
      rowsum += __shfl_xor(rowsum, 32);
      l_i[g] = l_i[g] * alpha + rowsum;
      m_i[g] = mnew;

      float arow[4];
      #pragma unroll
      for (int r = 0; r < 4; r++) arow[r] = __shfl(alpha, asrc + r);
      #pragma unroll
      for (int nt = 0; nt < 4; nt++)
        #pragma unroll
        for (int r = 0; r < 4; r++) o_acc[g][nt][r] *= arow[r];

      // P -> sP in A-layout (row = q = l16, cols = key); per-wave buffer,
      // reused across g: safe, a wave's DS ops execute in order.
      #pragma unroll
      for (int sub = 0; sub < 4; sub++){
        short4v pk;
        pk[0] = (short)f2b(p[sub][0]); pk[1] = (short)f2b(p[sub][1]);
        pk[2] = (short)f2b(p[sub][2]); pk[3] = (short)f2b(p[sub][3]);
        *reinterpret_cast<short4v*>(&sP[wave][l16*LDP + sub*16 + quad*4]) = pk;
      }
      const short8 pf0 = *reinterpret_cast<const short8*>(&sP[wave][l16*LDP + quad*8]);
      const short8 pf1 = *reinterpret_cast<const short8*>(&sP[wave][l16*LDP + 32 + quad*8]);
      #pragma unroll
      for (int nt = 0; nt < 4; nt++){
        const short8 vf0 = *reinterpret_cast<const short8*>(&sV[buf][0][(nt*16 + l16)*32 + qx]);
        const short8 vf1 = *reinterpret_cast<const short8*>(&sV[buf][1][(nt*16 + l16)*32 + qx]);
        o_acc[g][nt] = MFMA16(pf0, vf0, o_acc[g][nt]);
        o_acc[g][nt] = MFMA16(pf1, vf1, o_acc[g][nt]);
      }
    }
  }

  #pragma unroll
  for (int g = 0; g < 2; g++){
    float lrow[4];
    #pragma unroll
    for (int r = 0; r < 4; r++) lrow[r] = __shfl(l_i[g], asrc + r);
    #pragma unroll
    for (int nt = 0; nt < 4; nt++){
      #pragma unroll
      for (int r = 0; r < 4; r++){
        const int row = q0 + g*64 + wave*16 + quad*4 + r;
        O[(size_t)(b*T + row)*1024 + h*64 + nt*16 + l16] = f2b(o_acc[g][nt][r] / lrow[r]);
      }
    }
  }
}

// ---------------- launch ----------------
extern "C" void kernel_launch(void* const* d_in, const int* in_sizes, int n_in,
                              void* d_out, int out_size, void* d_ws, size_t ws_size,
                              hipStream_t stream){
  const float* x      = (const float*)d_in[0];
  const float* Wq     = (const float*)d_in[1];
  const float* bq     = (const float*)d_in[2];
  const float* Wk     = (const float*)d_in[3];
  const float* bk     = (const float*)d_in[4];
  const float* Wv     = (const float*)d_in[5];
  const float* bv     = (const float*)d_in[6];
  const float* Wo     = (const float*)d_in[7];
  const float* bo     = (const float*)d_in[8];
  const float* ln1_g  = (const float*)d_in[9];
  const float* ln1_b  = (const float*)d_in[10];
  const float* ln2_g  = (const float*)d_in[11];
  const float* ln2_b  = (const float*)d_in[12];
  const float* W_fc   = (const float*)d_in[13];
  const float* b_fc   = (const float*)d_in[14];
  const float* W_proj = (const float*)d_in[15];
  const float* b_proj = (const float*)d_in[16];
  float* out = (float*)d_out;
  char* ws = (char*)d_ws;
  const size_t MB = 1024 * 1024;

  u16* bufA  = (u16*)(ws);            // 16MB: xn -> attn_out -> h  [8192][1024]
  u16* qkvb  = (u16*)(ws + 16*MB);    // 48MB: [8192][3072] (V third unused)
  u16* vtb   = (u16*)(ws + 64*MB);    // 16MB: [64][64][2048] (written by QKV GEMM)
  u16* fcb   = (u16*)(ws + 16*MB);    // 64MB, reuses qkvb+vtb (dead after attn)
  float* x2  = out;                   // d_out doubles as fp32 residual buffer
  u16* Wqkvt = (u16*)(ws + 80*MB);    // 6MB: [3072][1024]
  u16* Wot   = (u16*)(ws + 86*MB);    // 2MB
  u16* Wfct  = (u16*)(ws + 88*MB);    // 8MB
  u16* Wpjt  = (u16*)(ws + 96*MB);    // 8MB
  float* bqkv= (float*)(ws + 104*MB); // 12KB

  dim3 tb(256);
  transpose_cvt<<<dim3(32, 32),  tb, 0, stream>>>(Wq,     Wqkvt,             1024, 1024);
  transpose_cvt<<<dim3(32, 32),  tb, 0, stream>>>(Wk,     Wqkvt + 1024*1024, 1024, 1024);
  transpose_cvt<<<dim3(32, 32),  tb, 0, stream>>>(Wv,     Wqkvt + 2048*1024, 1024, 1024);
  transpose_cvt<<<dim3(32, 32),  tb, 0, stream>>>(Wo,     Wot,               1024, 1024);
  transpose_cvt<<<dim3(128, 32), tb, 0, stream>>>(W_fc,   Wfct,              1024, 4096);
  transpose_cvt<<<dim3(32, 128), tb, 0, stream>>>(W_proj, Wpjt,              4096, 1024);
  bias_concat<<<dim3(12), tb, 0, stream>>>(bq, bk, bv, bqkv);

  ln_kernel<<<8192, tb, 0, stream>>>(x, ln1_g, ln1_b, bufA);

  // fused QKV: [8192,1024] @ [3072,1024]^T -> Q,K into qkvb; V^T into vtb
  gemm128<false,false,true,true><<<dim3(64,24), tb, 0, stream>>>(
      bufA, Wqkvt, bqkv, bqkv+1024, bqkv+2048, nullptr, nullptr, qkvb, vtb, 8192, 3072, 1024);

  attn_kernel<<<dim3(16, 64), tb, 0, stream>>>(qkvb, vtb, bufA);

  gemm128<false,true,false,false><<<dim3(64,8), tb, 0, stream>>>(
      bufA, Wot, bo, nullptr, nullptr, x, x2, nullptr, nullptr, 8192, 1024, 1024);

  ln_kernel<<<8192, tb, 0, stream>>>(x2, ln2_g, ln2_b, bufA);

  gemm128<true,false,true,false><<<dim3(64,32), tb, 0, stream>>>(
      bufA, Wfct, b_fc, nullptr, nullptr, nullptr, nullptr, fcb, nullptr, 8192, 4096, 1024);

  gemm128<false,true,false,false><<<dim3(64,8), tb, 0, stream>>>(
      fcb, Wpjt, b_proj, nullptr, nullptr, x2, out, nullptr, nullptr, 8192, 1024, 4096);
}

// Round 7
// 544.834 us; speedup vs baseline: 1.9807x; 1.0262x over previous
//
#include <hip/hip_runtime.h>

typedef __attribute__((ext_vector_type(8))) short short8;
typedef __attribute__((ext_vector_type(4))) short short4v;
typedef __attribute__((ext_vector_type(4))) float floatx4;
typedef unsigned short u16;

#define MFMA16(a,b,c) __builtin_amdgcn_mfma_f32_16x16x32_bf16(a,b,c,0,0,0)

typedef const __attribute__((address_space(1))) void* gas1;
typedef __attribute__((address_space(3))) void* las3;
static __device__ __forceinline__ void glds16(const void* g, void* l){
  __builtin_amdgcn_global_load_lds((gas1)g, (las3)l, 16, 0, 0);
}

// fp32 -> bf16 round-to-nearest-even
static __device__ __forceinline__ u16 f2b(float f){
  union { float f; unsigned int u; } c; c.f = f;
  unsigned int u = c.u;
  u += 0x7fffu + ((u >> 16) & 1u);
  return (u16)(u >> 16);
}

// ---------------- weight transpose + fp32->bf16: W[KxN] -> Wt[NxK] ----------------
__global__ __launch_bounds__(256) void transpose_cvt(
    const float* __restrict__ W, u16* __restrict__ Wt, int K, int N){
  __shared__ float tile[32][33];
  const int tx = threadIdx.x & 31;
  const int ty = threadIdx.x >> 5;
  const int nx = blockIdx.x * 32, kx = blockIdx.y * 32;
  #pragma unroll
  for (int i = ty; i < 32; i += 8)
    tile[i][tx] = W[(size_t)(kx + i) * N + nx + tx];
  __syncthreads();
  #pragma unroll
  for (int i = ty; i < 32; i += 8)
    Wt[(size_t)(nx + i) * K + kx + tx] = f2b(tile[tx][i]);
}

// ---------------- layernorm fp32 -> bf16, C=1024, 1 block/row ----------------
__global__ __launch_bounds__(256) void ln_kernel(
    const float* __restrict__ x, const float* __restrict__ g,
    const float* __restrict__ b, u16* __restrict__ out){
  const int row = blockIdx.x, tid = threadIdx.x;
  const float4 v = reinterpret_cast<const float4*>(x + (size_t)row * 1024)[tid];
  float s  = v.x + v.y + v.z + v.w;
  float s2 = v.x*v.x + v.y*v.y + v.z*v.z + v.w*v.w;
  #pragma unroll
  for (int off = 1; off < 64; off <<= 1){
    s  += __shfl_xor(s,  off);
    s2 += __shfl_xor(s2, off);
  }
  __shared__ float red[8];
  const int wave = tid >> 6, lane = tid & 63;
  if (lane == 0){ red[wave] = s; red[4 + wave] = s2; }
  __syncthreads();
  s  = red[0] + red[1] + red[2] + red[3];
  s2 = red[4] + red[5] + red[6] + red[7];
  const float mu  = s * (1.f/1024.f);
  const float var = s2 * (1.f/1024.f) - mu * mu;
  const float rs  = rsqrtf(var + 1e-5f);
  const float4 gg = reinterpret_cast<const float4*>(g)[tid];
  const float4 bb = reinterpret_cast<const float4*>(b)[tid];
  ushort4 o;
  o.x = f2b((v.x - mu) * rs * gg.x + bb.x);
  o.y = f2b((v.y - mu) * rs * gg.y + bb.y);
  o.z = f2b((v.z - mu) * rs * gg.z + bb.z);
  o.w = f2b((v.w - mu) * rs * gg.w + bb.w);
  reinterpret_cast<ushort4*>(out + (size_t)row * 1024)[tid] = o;
}

// ---------------- bias concat for fused QKV ----------------
__global__ __launch_bounds__(256) void bias_concat(
    const float* __restrict__ bq, const float* __restrict__ bk,
    const float* __restrict__ bv, float* __restrict__ o){
  const int i = blockIdx.x * 256 + threadIdx.x;
  if (i < 1024) o[i] = bq[i];
  else if (i < 2048) o[i] = bk[i - 1024];
  else if (i < 3072) o[i] = bv[i - 2048];
}

// ---------------- GEMM: 128x128 tile, BK=32 double-buffered, permuted-B epilogue ------
// A: MxK bf16; Bt: NxK bf16; out = epilogue(A @ Bt^T + bias [+res]); K % 32 == 0.
// XOR bank swizzle: LDS slot (row, chunk c) holds global chunk (c ^ ((slotrow>>1)&3)).
// B rows are PERMUTED at staging: LDS slot nt*16+l16 holds global col 4*l16+nt of its
// 64-half, so each lane's 4 nt-accumulators are 4 ADJACENT columns -> packed stores.
// QKVMODE: blocks with n0>=2048 write V^T to vtb ([bh][d][t]); bias = concat qkv bias.
template<bool GELU, bool RES, bool OUTBF, bool QKVMODE>
__global__ __launch_bounds__(256) void gemm128(
    const u16* __restrict__ A, const u16* __restrict__ Bt,
    const float* __restrict__ bias,
    const float* __restrict__ res,
    float* __restrict__ outF, u16* __restrict__ outB,
    u16* __restrict__ vtb,
    int M, int N, int K)
{
  __shared__ __attribute__((aligned(16))) u16 sA[2][128 * 32];
  __shared__ __attribute__((aligned(16))) u16 sB[2][128 * 32];
  const int tid  = threadIdx.x;
  const int wave = tid >> 6, lane = tid & 63, quad = lane >> 4, l16 = lane & 15;
  const int m0 = blockIdx.x * 128, n0 = blockIdx.y * 128;
  const int wm = (wave >> 1) * 64, wn = (wave & 1) * 64;

  const int scol = ((lane & 3) ^ ((lane >> 3) & 3)) * 8;
  const size_t aoff  = (size_t)(m0 + wave*32 + (lane >> 2)) * K + scol;
  const size_t aoff2 = aoff + (size_t)16 * K;
  // permuted B rows: wave w, issue h stages global col n0+(w>>1)*64+4*(L>>2)+(w&1)*2+h
  const int brow = n0 + (wave >> 1)*64 + 4*(lane >> 2) + (wave & 1)*2;
  const size_t boff  = (size_t)brow * K + scol;
  const size_t boff2 = boff + (size_t)K;
  u16* alp = sA[0] + wave * 1024;
  u16* blp = sB[0] + wave * 1024;
  const int qx = (quad ^ ((l16 >> 1) & 3)) * 8;

  floatx4 acc[4][4];
  #pragma unroll
  for (int i = 0; i < 4; i++)
    #pragma unroll
    for (int nt = 0; nt < 4; nt++) acc[i][nt] = floatx4{0.f,0.f,0.f,0.f};

  // prefetch k0 = 0 into buf 0
  glds16(A  + aoff,  alp);
  glds16(A  + aoff2, alp + 512);
  glds16(Bt + boff,  blp);
  glds16(Bt + boff2, blp + 512);

  int buf = 0;
  for (int k0 = 0; k0 < K; k0 += 32, buf ^= 1){
    __syncthreads();   // buf's loads drained (issued one compute-phase ago); buf^1 free
    if (k0 + 32 < K){
      const int kn = k0 + 32;
      const int bo = (buf ^ 1) * 4096;
      glds16(A  + aoff  + kn, alp + bo);
      glds16(A  + aoff2 + kn, alp + bo + 512);
      glds16(Bt + boff  + kn, blp + bo);
      glds16(Bt + boff2 + kn, blp + bo + 512);
    }
    const u16* sa = sA[buf];
    const u16* sb = sB[buf];
    short8 af[4], bf[4];
    #pragma unroll
    for (int i = 0; i < 4; i++)
      af[i] = *reinterpret_cast<const short8*>(&sa[(wm + i*16 + l16)*32 + qx]);
    #pragma unroll
    for (int nt = 0; nt < 4; nt++)
      bf[nt] = *reinterpret_cast<const short8*>(&sb[(wn + nt*16 + l16)*32 + qx]);
    #pragma unroll
    for (int i = 0; i < 4; i++)
      #pragma unroll
      for (int nt = 0; nt < 4; nt++)
        acc[i][nt] = MFMA16(af[i], bf[nt], acc[i][nt]);
  }

  const int col0 = n0 + wn + 4*l16;   // lane's 4 columns: col0..col0+3
  const floatx4 bi = *reinterpret_cast<const floatx4*>(&bias[col0]);

  if (QKVMODE && n0 >= 2048){
    // V^T epilogue: vtb[bh][d][t], 4 consecutive t per lane -> packed 8B stores
    #pragma unroll
    for (int nt = 0; nt < 4; nt++){
      const int hd = col0 + nt - 2048;   // h*64 + d
      u16* vcol = vtb + (size_t)(hd >> 6) * 131072 + (size_t)(hd & 63) * 2048;
      #pragma unroll
      for (int i = 0; i < 4; i++){
        const int t0 = m0 + wm + i*16 + quad*4;      // global row (b,t)
        const int bb = t0 >> 11, tt = t0 & 2047;
        short4v pk;
        #pragma unroll
        for (int r = 0; r < 4; r++) pk[r] = (short)f2b(acc[i][nt][r] + bi[nt]);
        *reinterpret_cast<short4v*>(vcol + (size_t)bb * 2097152 + tt) = pk;
      }
    }
    return;
  }

  #pragma unroll
  for (int i = 0; i < 4; i++){
    #pragma unroll
    for (int r = 0; r < 4; r++){
      const int row = m0 + wm + i*16 + quad*4 + r;
      if (OUTBF){
        short4v o;
        #pragma unroll
        for (int nt = 0; nt < 4; nt++){
          float val = acc[i][nt][r] + bi[nt];
          if (GELU){
            const float t = 0.7978845608028654f * (val + 0.044715f * val * val * val);
            val = val / (1.f + __expf(-2.f * t));   // 0.5v(1+tanh t) == v*sigmoid(2t)
          }
          o[nt] = (short)f2b(val);
        }
        *reinterpret_cast<short4v*>(&outB[(size_t)row * N + col0]) = o;
      } else {
        floatx4 v;
        #pragma unroll
        for (int nt = 0; nt < 4; nt++) v[nt] = acc[i][nt][r] + bi[nt];
        if (RES){
          const floatx4 rr = *reinterpret_cast<const floatx4*>(&res[(size_t)row * N + col0]);
          #pragma unroll
          for (int nt = 0; nt < 4; nt++) v[nt] += rr[nt];
        }
        *reinterpret_cast<floatx4*>(&outF[(size_t)row * N + col0]) = v;
      }
    }
  }
}

// ---------------- flash attention (transposed-S), causal, D=64, H=16, T=2048 ----------------
// 128 Q-rows per block; length-balanced q-tile permutation; double-buffered K/V
// prefetch with ONE barrier per tile-iteration.
// grid (16, 64)
__global__ __launch_bounds__(256) void attn_kernel(
    const u16* __restrict__ qkv, const u16* __restrict__ vtb,
    u16* __restrict__ O)
{
  constexpr int T = 2048, LDQ = 3072, LDP = 72;
  __shared__ __attribute__((aligned(16))) u16 sK[2][2][64*32];
  __shared__ __attribute__((aligned(16))) u16 sV[2][2][64*32];
  __shared__ __attribute__((aligned(16))) u16 sP[4][16*LDP];

  const int tid = threadIdx.x, wave = tid >> 6, lane = tid & 63;
  const int quad = lane >> 4, l16 = lane & 15;

  // Length-balanced tile assignment: for any CU receiving blocks strided by 256
  // in linear id, the four causal lengths sum to the same total (68 iters).
  const int lin = blockIdx.y * 16 + blockIdx.x;
  const int j = lin & 15;
  const int bh = lin >> 4;              // 0..63 (head slot)
  const int kk4 = bh >> 4;              // 0..3
  const int jj = (j + ((kk4 & 2) << 2)) & 15;
  const int qt = (kk4 & 1) ? (15 - jj) : jj;
  const int q0 = qt * 128;
  const int b = bh >> 4, h = bh & 15;

  const u16* Qp = qkv + (size_t)b * T * LDQ + h * 64;
  const u16* Kp = Qp + 1024;
  const u16* Vt = vtb + (size_t)bh * 64 * T;

  const int qx = (quad ^ ((l16 >> 1) & 3)) * 8;       // swizzled fragment chunk

  int qg[2]; qg[0] = q0 + wave*16 + l16; qg[1] = qg[0] + 64;
  short8 qf[2][2];
  #pragma unroll
  for (int g = 0; g < 2; g++){
    qf[g][0] = *reinterpret_cast<const short8*>(&Qp[(size_t)qg[g]*LDQ + quad*8]);
    qf[g][1] = *reinterpret_cast<const short8*>(&Qp[(size_t)qg[g]*LDQ + 32 + quad*8]);
  }

  float m_i[2] = {-INFINITY, -INFINITY}, l_i[2] = {0.f, 0.f};
  floatx4 o_acc[2][4];
  #pragma unroll
  for (int g = 0; g < 2; g++)
    #pragma unroll
    for (int nt = 0; nt < 4; nt++) o_acc[g][nt] = floatx4{0.f,0.f,0.f,0.f};

  // staging: row = wave*16 + (lane>>2); col chunk XOR-swizzled by (row>>1)&3
  const int srow = wave*16 + (lane >> 2);
  const int scol = ((lane & 3) ^ ((lane >> 3) & 3)) * 8;
  const int asrc = (lane & 48) | (quad * 4);   // shfl source: lane owning q-row quad*4+r

  const int kend = q0 + 128;

  // prefetch tile 0 into buf 0
  {
    glds16(Kp + (size_t)srow*LDQ + scol,      sK[0][0] + wave*512);
    glds16(Kp + (size_t)srow*LDQ + 32 + scol, sK[0][1] + wave*512);
    glds16(Vt + (size_t)srow*T + scol,        sV[0][0] + wave*512);
    glds16(Vt + (size_t)srow*T + 32 + scol,   sV[0][1] + wave*512);
  }

  int buf = 0;
  for (int k0 = 0; k0 < kend; k0 += 64, buf ^= 1){
    __syncthreads();   // staged tile `buf` ready; all waves past reads of buf^1
    if (k0 + 64 < kend){
      const int kn = k0 + 64;
      glds16(Kp + (size_t)(kn + srow)*LDQ + scol,      sK[buf^1][0] + wave*512);
      glds16(Kp + (size_t)(kn + srow)*LDQ + 32 + scol, sK[buf^1][1] + wave*512);
      glds16(Vt + (size_t)srow*T + kn + scol,          sV[buf^1][0] + wave*512);
      glds16(Vt + (size_t)srow*T + kn + 32 + scol,     sV[buf^1][1] + wave*512);
    }

    #pragma unroll
    for (int g = 0; g < 2; g++){
      if (g == 0 && k0 > q0) continue;   // tile fully masked for group 0

      // S^T = K·Q^T : s[sub][r] = score(key = k0+sub*16+quad*4+r, q = qg[g])
      float s[4][4];
      #pragma unroll
      for (int sub = 0; sub < 4; sub++){
        floatx4 sa = floatx4{0.f,0.f,0.f,0.f};
        const short8 kf0 = *reinterpret_cast<const short8*>(&sK[buf][0][(sub*16 + l16)*32 + qx]);
        const short8 kf1 = *reinterpret_cast<const short8*>(&sK[buf][1][(sub*16 + l16)*32 + qx]);
        sa = MFMA16(kf0, qf[g][0], sa);
        sa = MFMA16(kf1, qf[g][1], sa);
        #pragma unroll
        for (int r = 0; r < 4; r++) s[sub][r] = sa[r];
      }
      if (k0 == q0 + g*64){   // diagonal tile for this group
        #pragma unroll
        for (int sub = 0; sub < 4; sub++)
          #pragma unroll
          for (int r = 0; r < 4; r++){
            const int kidx = k0 + sub*16 + quad*4 + r;
            if (kidx > qg[g]) s[sub][r] = -1e30f;
          }
      }

      // in-lane softmax over 16 scores; cross-quad reduce with 2 shuffles
      float mx = s[0][0];
      #pragma unroll
      for (int sub = 0; sub < 4; sub++)
        #pragma unroll
        for (int r = 0; r < 4; r++) mx = fmaxf(mx, s[sub][r]);
      mx = fmaxf(mx, __shfl_xor(mx, 16));
      mx = fmaxf(mx, __shfl_xor(mx, 32));
      const float mnew  = fmaxf(m_i[g], mx);
      const float alpha = __expf(0.125f * (m_i[g] - mnew));
      float p[4][4], rowsum = 0.f;
      #pragma unroll
      for (int sub = 0; sub < 4; sub++)
        #pragma unroll
        for (int r = 0; r < 4; r++){
          p[sub][r] = __expf(0.125f * (s[sub][r] - mnew));
          rowsum += p[sub][r];
        }
      rowsum += __shfl_xor(rowsum, 16);
      rowsum += __shfl_xor(rowsum, 32);
      l_i[g] = l_i[g] * alpha + rowsum;
      m_i[g] = mnew;

      float arow[4];
      #pragma unroll
      for (int r = 0; r < 4; r++) arow[r] = __shfl(alpha, asrc + r);
      #pragma unroll
      for (int nt = 0; nt < 4; nt++)
        #pragma unroll
        for (int r = 0; r < 4; r++) o_acc[g][nt][r] *= arow[r];

      // P -> sP in A-layout (row = q = l16, cols = key); per-wave buffer,
      // reused across g: safe, a wave's DS ops execute in order.
      #pragma unroll
      for (int sub = 0; sub < 4; sub++){
        short4v pk;
        pk[0] = (short)f2b(p[sub][0]); pk[1] = (short)f2b(p[sub][1]);
        pk[2] = (short)f2b(p[sub][2]); pk[3] = (short)f2b(p[sub][3]);
        *reinterpret_cast<short4v*>(&sP[wave][l16*LDP + sub*16 + quad*4]) = pk;
      }
      const short8 pf0 = *reinterpret_cast<const short8*>(&sP[wave][l16*LDP + quad*8]);
      const short8 pf1 = *reinterpret_cast<const short8*>(&sP[wave][l16*LDP + 32 + quad*8]);
      #pragma unroll
      for (int nt = 0; nt < 4; nt++){
        const short8 vf0 = *reinterpret_cast<const short8*>(&sV[buf][0][(nt*16 + l16)*32 + qx]);
        const short8 vf1 = *reinterpret_cast<const short8*>(&sV[buf][1][(nt*16 + l16)*32 + qx]);
        o_acc[g][nt] = MFMA16(pf0, vf0, o_acc[g][nt]);
        o_acc[g][nt] = MFMA16(pf1, vf1, o_acc[g][nt]);
      }
    }
  }

  #pragma unroll
  for (int g = 0; g < 2; g++){
    float lrow[4];
    #pragma unroll
    for (int r = 0; r < 4; r++) lrow[r] = __shfl(l_i[g], asrc + r);
    #pragma unroll
    for (int nt = 0; nt < 4; nt++){
      #pragma unroll
      for (int r = 0; r < 4; r++){
        const int row = q0 + g*64 + wave*16 + quad*4 + r;
        O[(size_t)(b*T + row)*1024 + h*64 + nt*16 + l16] = f2b(o_acc[g][nt][r] / lrow[r]);
      }
    }
  }
}

// ---------------- launch ----------------
extern "C" void kernel_launch(void* const* d_in, const int* in_sizes, int n_in,
                              void* d_out, int out_size, void* d_ws, size_t ws_size,
                              hipStream_t stream){
  const float* x      = (const float*)d_in[0];
  const float* Wq     = (const float*)d_in[1];
  const float* bq     = (const float*)d_in[2];
  const float* Wk     = (const float*)d_in[3];
  const float* bk     = (const float*)d_in[4];
  const float* Wv     = (const float*)d_in[5];
  const float* bv     = (const float*)d_in[6];
  const float* Wo     = (const float*)d_in[7];
  const float* bo     = (const float*)d_in[8];
  const float* ln1_g  = (const float*)d_in[9];
  const float* ln1_b  = (const float*)d_in[10];
  const float* ln2_g  = (const float*)d_in[11];
  const float* ln2_b  = (const float*)d_in[12];
  const float* W_fc   = (const float*)d_in[13];
  const float* b_fc   = (const float*)d_in[14];
  const float* W_proj = (const float*)d_in[15];
  const float* b_proj = (const float*)d_in[16];
  float* out = (float*)d_out;
  char* ws = (char*)d_ws;
  const size_t MB = 1024 * 1024;

  u16* bufA  = (u16*)(ws);            // 16MB: xn -> attn_out -> h  [8192][1024]
  u16* qkvb  = (u16*)(ws + 16*MB);    // 48MB: [8192][3072] (V third unused)
  u16* vtb   = (u16*)(ws + 64*MB);    // 16MB: [64][64][2048] (written by QKV GEMM)
  u16* fcb   = (u16*)(ws + 16*MB);    // 64MB, reuses qkvb+vtb (dead after attn)
  float* x2  = out;                   // d_out doubles as fp32 residual buffer
  u16* Wqkvt = (u16*)(ws + 80*MB);    // 6MB: [3072][1024]
  u16* Wot   = (u16*)(ws + 86*MB);    // 2MB
  u16* Wfct  = (u16*)(ws + 88*MB);    // 8MB
  u16* Wpjt  = (u16*)(ws + 96*MB);    // 8MB
  float* bqkv= (float*)(ws + 104*MB); // 12KB

  dim3 tb(256);
  transpose_cvt<<<dim3(32, 32),  tb, 0, stream>>>(Wq,     Wqkvt,             1024, 1024);
  transpose_cvt<<<dim3(32, 32),  tb, 0, stream>>>(Wk,     Wqkvt + 1024*1024, 1024, 1024);
  transpose_cvt<<<dim3(32, 32),  tb, 0, stream>>>(Wv,     Wqkvt + 2048*1024, 1024, 1024);
  transpose_cvt<<<dim3(32, 32),  tb, 0, stream>>>(Wo,     Wot,               1024, 1024);
  transpose_cvt<<<dim3(128, 32), tb, 0, stream>>>(W_fc,   Wfct,              1024, 4096);
  transpose_cvt<<<dim3(32, 128), tb, 0, stream>>>(W_proj, Wpjt,              4096, 1024);
  bias_concat<<<dim3(12), tb, 0, stream>>>(bq, bk, bv, bqkv);

  ln_kernel<<<8192, tb, 0, stream>>>(x, ln1_g, ln1_b, bufA);

  // fused QKV: [8192,1024] @ [3072,1024]^T -> Q,K into qkvb; V^T into vtb
  gemm128<false,false,true,true><<<dim3(64,24), tb, 0, stream>>>(
      bufA, Wqkvt, bqkv, nullptr, nullptr, qkvb, vtb, 8192, 3072, 1024);

  attn_kernel<<<dim3(16, 64), tb, 0, stream>>>(qkvb, vtb, bufA);

  gemm128<false,true,false,false><<<dim3(64,8), tb, 0, stream>>>(
      bufA, Wot, bo, x, x2, nullptr, nullptr, 8192, 1024, 1024);

  ln_kernel<<<8192, tb, 0, stream>>>(x2, ln2_g, ln2_b, bufA);

  gemm128<true,false,true,false><<<dim3(64,32), tb, 0, stream>>>(
      bufA, Wfct, b_fc, nullptr, nullptr, fcb, nullptr, 8192, 4096, 1024);

  gemm128<false,true,false,false><<<dim3(64,8), tb, 0, stream>>>(
      fcb, Wpjt, b_proj, x2, out, nullptr, nullptr, 8192, 1024, 4096);
}